// Round 1
// baseline (8622.967 us; speedup 1.0000x reference)
//
#include <hip/hip_runtime.h>

__device__ __forceinline__ float lrelu(float v){ return v > 0.f ? v : 0.01f*v; }

// ---------------- conv1 edge phase: agg1[dst] += relu(x[src] + ea@We1 + be1) ----
__global__ __launch_bounds__(256) void k_edge1(
    const float* __restrict__ x, const int* __restrict__ ei,
    const float* __restrict__ ea, const float* __restrict__ We,
    const float* __restrict__ be, float* __restrict__ agg, int E)
{
    int e = blockIdx.x * 256 + threadIdx.x;
    if (e >= E) return;
    int s = ei[e];        // src = edge_index[0]
    int d = ei[E + e];    // dst = edge_index[1]
    float av[16];
    {
        const float4* p = reinterpret_cast<const float4*>(ea) + (size_t)e * 4;
        #pragma unroll
        for (int q = 0; q < 4; ++q) {
            float4 v = p[q];
            av[4*q+0]=v.x; av[4*q+1]=v.y; av[4*q+2]=v.z; av[4*q+3]=v.w;
        }
    }
    float xv[32];
    {
        const float4* p = reinterpret_cast<const float4*>(x) + (size_t)s * 8;
        #pragma unroll
        for (int q = 0; q < 8; ++q) {
            float4 v = p[q];
            xv[4*q+0]=v.x; xv[4*q+1]=v.y; xv[4*q+2]=v.z; xv[4*q+3]=v.w;
        }
    }
    float* aggd = agg + (size_t)d * 32;
    #pragma unroll
    for (int c = 0; c < 32; ++c) {
        float v = be[c];
        #pragma unroll
        for (int k = 0; k < 16; ++k) v = fmaf(av[k], We[k*32+c], v);
        v += xv[c];
        v = v > 0.f ? v : 0.f;
        atomicAdd(aggd + c, v);
    }
}

// ---------------- conv2 edge phase: agg2[dst] += relu(h1[src] + ea@We2 + be2) ---
__global__ __launch_bounds__(256) void k_edge2(
    const float* __restrict__ h1, const int* __restrict__ ei,
    const float* __restrict__ ea, const float* __restrict__ We,
    const float* __restrict__ be, float* __restrict__ agg, int E)
{
    int e = blockIdx.x * 256 + threadIdx.x;
    if (e >= E) return;
    int s = ei[e];
    int d = ei[E + e];
    float av[16];
    {
        const float4* p = reinterpret_cast<const float4*>(ea) + (size_t)e * 4;
        #pragma unroll
        for (int q = 0; q < 4; ++q) {
            float4 v = p[q];
            av[4*q+0]=v.x; av[4*q+1]=v.y; av[4*q+2]=v.z; av[4*q+3]=v.w;
        }
    }
    float hv[64];
    {
        const float4* p = reinterpret_cast<const float4*>(h1) + (size_t)s * 16;
        #pragma unroll
        for (int q = 0; q < 16; ++q) {
            float4 v = p[q];
            hv[4*q+0]=v.x; hv[4*q+1]=v.y; hv[4*q+2]=v.z; hv[4*q+3]=v.w;
        }
    }
    float* aggd = agg + (size_t)d * 64;
    #pragma unroll
    for (int c = 0; c < 64; ++c) {
        float v = be[c];
        #pragma unroll
        for (int k = 0; k < 16; ++k) v = fmaf(av[k], We[k*64+c], v);
        v += hv[c];
        v = v > 0.f ? v : 0.f;
        atomicAdd(aggd + c, v);
    }
}

// ---------------- conv1 node nn: h1 = lrelu( lrelu((x+agg1)@W1a+b1a)@W1b + b1b )
__global__ __launch_bounds__(256) void k_mlp1(
    const float* __restrict__ x, const float* __restrict__ agg1,
    const float* __restrict__ W1a, const float* __restrict__ b1a,
    const float* __restrict__ W1b, const float* __restrict__ b1b,
    float* __restrict__ h1, int N)
{
    int n = blockIdx.x * 256 + threadIdx.x;
    if (n >= N) return;
    float h[32];
    {
        const float4* xp = reinterpret_cast<const float4*>(x) + (size_t)n * 8;
        const float4* ap = reinterpret_cast<const float4*>(agg1) + (size_t)n * 8;
        #pragma unroll
        for (int q = 0; q < 8; ++q) {
            float4 a = xp[q], b = ap[q];
            h[4*q+0]=a.x+b.x; h[4*q+1]=a.y+b.y; h[4*q+2]=a.z+b.z; h[4*q+3]=a.w+b.w;
        }
    }
    float t[32];
    #pragma unroll
    for (int c = 0; c < 32; ++c) {
        float v = b1a[c];
        #pragma unroll
        for (int k = 0; k < 32; ++k) v = fmaf(h[k], W1a[k*32+c], v);
        t[c] = lrelu(v);
    }
    const float4* W1b4 = reinterpret_cast<const float4*>(W1b);
    const float4* b1b4 = reinterpret_cast<const float4*>(b1b);
    float4* op = reinterpret_cast<float4*>(h1) + (size_t)n * 16;
    for (int cq = 0; cq < 16; ++cq) {      // runtime loop, 4 outputs/iter
        float4 bv = b1b4[cq];
        float a0 = bv.x, a1 = bv.y, a2 = bv.z, a3 = bv.w;
        #pragma unroll
        for (int k = 0; k < 32; ++k) {
            float4 w = W1b4[k*16 + cq];
            a0 = fmaf(t[k], w.x, a0); a1 = fmaf(t[k], w.y, a1);
            a2 = fmaf(t[k], w.z, a2); a3 = fmaf(t[k], w.w, a3);
        }
        float4 o; o.x = lrelu(a0); o.y = lrelu(a1); o.z = lrelu(a2); o.w = lrelu(a3);
        op[cq] = o;
    }
}

// ---------------- conv2 nn layer 1: t = lrelu((h1+agg2)@W2a + b2a)  [N,128] ----
__global__ __launch_bounds__(256) void k_mlp2a(
    const float* __restrict__ h1, const float* __restrict__ agg2,
    const float* __restrict__ W2a, const float* __restrict__ b2a,
    float* __restrict__ t, int N)
{
    int n = blockIdx.x * 256 + threadIdx.x;
    if (n >= N) return;
    float h[64];
    {
        const float4* xp = reinterpret_cast<const float4*>(h1) + (size_t)n * 16;
        const float4* ap = reinterpret_cast<const float4*>(agg2) + (size_t)n * 16;
        #pragma unroll
        for (int q = 0; q < 16; ++q) {
            float4 a = xp[q], b = ap[q];
            h[4*q+0]=a.x+b.x; h[4*q+1]=a.y+b.y; h[4*q+2]=a.z+b.z; h[4*q+3]=a.w+b.w;
        }
    }
    const float4* W4 = reinterpret_cast<const float4*>(W2a);
    const float4* b4 = reinterpret_cast<const float4*>(b2a);
    float4* op = reinterpret_cast<float4*>(t) + (size_t)n * 32;
    for (int cq = 0; cq < 32; ++cq) {
        float4 bv = b4[cq];
        float a0 = bv.x, a1 = bv.y, a2 = bv.z, a3 = bv.w;
        #pragma unroll
        for (int k = 0; k < 64; ++k) {
            float4 w = W4[k*32 + cq];
            a0 = fmaf(h[k], w.x, a0); a1 = fmaf(h[k], w.y, a1);
            a2 = fmaf(h[k], w.z, a2); a3 = fmaf(h[k], w.w, a3);
        }
        float4 o; o.x = lrelu(a0); o.y = lrelu(a1); o.z = lrelu(a2); o.w = lrelu(a3);
        op[cq] = o;
    }
}

// ---------------- conv2 nn layer 2: h2 = lrelu(t@W2b + b2b)  [N,256] -----------
__global__ __launch_bounds__(256) void k_mlp2b(
    const float* __restrict__ t, const float* __restrict__ W2b,
    const float* __restrict__ b2b, float* __restrict__ h2, int N)
{
    int n = blockIdx.x * 256 + threadIdx.x;
    if (n >= N) return;
    float tv[128];
    {
        const float4* p = reinterpret_cast<const float4*>(t) + (size_t)n * 32;
        #pragma unroll
        for (int q = 0; q < 32; ++q) {
            float4 v = p[q];
            tv[4*q+0]=v.x; tv[4*q+1]=v.y; tv[4*q+2]=v.z; tv[4*q+3]=v.w;
        }
    }
    const float4* W4 = reinterpret_cast<const float4*>(W2b);
    const float4* b4 = reinterpret_cast<const float4*>(b2b);
    float4* op = reinterpret_cast<float4*>(h2) + (size_t)n * 64;
    for (int cq = 0; cq < 64; ++cq) {
        float4 bv = b4[cq];
        float a0 = bv.x, a1 = bv.y, a2 = bv.z, a3 = bv.w;
        #pragma unroll
        for (int k = 0; k < 128; ++k) {
            float4 w = W4[k*64 + cq];
            a0 = fmaf(tv[k], w.x, a0); a1 = fmaf(tv[k], w.y, a1);
            a2 = fmaf(tv[k], w.z, a2); a3 = fmaf(tv[k], w.w, a3);
        }
        float4 o; o.x = lrelu(a0); o.y = lrelu(a1); o.z = lrelu(a2); o.w = lrelu(a3);
        op[cq] = o;
    }
}

// ---------------- global_add_pool over sorted batch ids ------------------------
__global__ __launch_bounds__(256) void k_pool(
    const float* __restrict__ h2, const int* __restrict__ batch,
    float* __restrict__ g, int N)
{
    int c = threadIdx.x;             // channel 0..255
    int n0 = blockIdx.x * 128;
    int nend = n0 + 128; if (nend > N) nend = N;
    float acc = 0.f;
    int cur = batch[n0];             // uniform
    for (int n = n0; n < nend; ++n) {
        int b = batch[n];            // uniform (sorted)
        if (b != cur) {
            atomicAdd(&g[(size_t)cur*256 + c], acc);
            acc = 0.f; cur = b;
        }
        acc += h2[(size_t)n*256 + c];
    }
    atomicAdd(&g[(size_t)cur*256 + c], acc);
}

// ---------------- head MLP: one block per graph --------------------------------
__global__ __launch_bounds__(256) void k_head(
    const float* __restrict__ g,
    const float* __restrict__ Wf0, const float* __restrict__ bf0,
    const float* __restrict__ Wf1, const float* __restrict__ bf1,
    const float* __restrict__ Wf2, const float* __restrict__ bf2,
    const float* __restrict__ Wr,  const float* __restrict__ br,
    float* __restrict__ out)
{
    __shared__ float buf[256];
    __shared__ float t0[128];
    __shared__ float t1[64];
    __shared__ float t2[32];
    int gid = blockIdx.x, tid = threadIdx.x;
    buf[tid] = g[(size_t)gid*256 + tid];
    __syncthreads();
    if (tid < 128) {
        float acc = bf0[tid];
        for (int k = 0; k < 256; ++k) acc = fmaf(buf[k], Wf0[k*128 + tid], acc);
        t0[tid] = lrelu(acc);
    }
    __syncthreads();
    if (tid < 64) {
        float acc = bf1[tid];
        for (int k = 0; k < 128; ++k) acc = fmaf(t0[k], Wf1[k*64 + tid], acc);
        t1[tid] = lrelu(acc);
    }
    __syncthreads();
    if (tid < 32) {
        float acc = bf2[tid];
        for (int k = 0; k < 64; ++k) acc = fmaf(t1[k], Wf2[k*32 + tid], acc);
        t2[tid] = lrelu(acc);
    }
    __syncthreads();
    if (tid == 0) {
        float acc = br[0];
        for (int k = 0; k < 32; ++k) acc = fmaf(t2[k], Wr[k], acc);
        out[gid] = acc;
    }
}

extern "C" void kernel_launch(void* const* d_in, const int* in_sizes, int n_in,
                              void* d_out, int out_size, void* d_ws, size_t ws_size,
                              hipStream_t stream)
{
    const float* x     = (const float*)d_in[0];
    const int*   ei    = (const int*)d_in[1];
    const float* ea    = (const float*)d_in[2];
    const int*   batch = (const int*)d_in[3];
    const float* We1=(const float*)d_in[4],  *be1=(const float*)d_in[5];
    const float* W1a=(const float*)d_in[6],  *b1a=(const float*)d_in[7];
    const float* W1b=(const float*)d_in[8],  *b1b=(const float*)d_in[9];
    const float* We2=(const float*)d_in[10], *be2=(const float*)d_in[11];
    const float* W2a=(const float*)d_in[12], *b2a=(const float*)d_in[13];
    const float* W2b=(const float*)d_in[14], *b2b=(const float*)d_in[15];
    const float* Wf0=(const float*)d_in[16], *bf0=(const float*)d_in[17];
    const float* Wf1=(const float*)d_in[18], *bf1=(const float*)d_in[19];
    const float* Wf2=(const float*)d_in[20], *bf2=(const float*)d_in[21];
    const float* Wr =(const float*)d_in[22], *br =(const float*)d_in[23];

    const int N = in_sizes[0] / 32;
    const int E = in_sizes[1] / 2;
    const int G = out_size;

    // workspace layout (floats): [agg1 N*32][agg2 N*64][g G*256] <- zeroed
    //                            [h1 N*64][t N*128][h2 N*256]
    float* agg1 = (float*)d_ws;
    float* agg2 = agg1 + (size_t)N*32;
    float* gbuf = agg2 + (size_t)N*64;
    float* h1   = gbuf + (size_t)G*256;
    float* tbuf = h1   + (size_t)N*64;
    float* h2   = tbuf + (size_t)N*128;

    size_t zero_bytes = ((size_t)N*32 + (size_t)N*64 + (size_t)G*256) * sizeof(float);
    hipMemsetAsync(d_ws, 0, zero_bytes, stream);

    int eb = (E + 255) / 256;
    int nb = (N + 255) / 256;

    k_edge1<<<eb, 256, 0, stream>>>(x, ei, ea, We1, be1, agg1, E);
    k_mlp1 <<<nb, 256, 0, stream>>>(x, agg1, W1a, b1a, W1b, b1b, h1, N);
    k_edge2<<<eb, 256, 0, stream>>>(h1, ei, ea, We2, be2, agg2, E);
    k_mlp2a<<<nb, 256, 0, stream>>>(h1, agg2, W2a, b2a, tbuf, N);
    k_mlp2b<<<nb, 256, 0, stream>>>(tbuf, W2b, b2b, h2, N);
    k_pool <<<(N + 127) / 128, 256, 0, stream>>>(h2, batch, gbuf, N);
    k_head <<<G, 256, 0, stream>>>(gbuf, Wf0, bf0, Wf1, bf1, Wf2, bf2, Wr, br,
                                   (float*)d_out);
}

// Round 2
// 1334.023 us; speedup vs baseline: 6.4639x; 6.4639x over previous
//
#include <hip/hip_runtime.h>

__device__ __forceinline__ float lrelu(float v){ return v > 0.f ? v : 0.01f*v; }

// ================= CSR build =================================================
__global__ __launch_bounds__(256) void k_hist(
    const int* __restrict__ ei, int* __restrict__ deg, int E)
{
    int e = blockIdx.x * 256 + threadIdx.x;
    if (e >= E) return;
    atomicAdd(&deg[ei[E + e]], 1);
}

__global__ __launch_bounds__(256) void k_scan1(
    const int* __restrict__ deg, int* __restrict__ rowptr,
    int* __restrict__ bsum, int N)
{
    __shared__ int sh[256];
    int t = threadIdx.x;
    int i = blockIdx.x * 256 + t;
    int v = (i < N) ? deg[i] : 0;
    sh[t] = v;
    __syncthreads();
    #pragma unroll
    for (int off = 1; off < 256; off <<= 1) {
        int add = (t >= off) ? sh[t - off] : 0;
        __syncthreads();
        sh[t] += add;
        __syncthreads();
    }
    if (i < N) rowptr[i] = sh[t] - v;      // exclusive within block
    if (t == 255) bsum[blockIdx.x] = sh[t];
}

__global__ __launch_bounds__(512) void k_scan2(int* __restrict__ bsum, int nb)
{
    __shared__ int sh[512];
    int t = threadIdx.x;
    int v = (t < nb) ? bsum[t] : 0;
    sh[t] = v;
    __syncthreads();
    #pragma unroll
    for (int off = 1; off < 512; off <<= 1) {
        int add = (t >= off) ? sh[t - off] : 0;
        __syncthreads();
        sh[t] += add;
        __syncthreads();
    }
    if (t < nb) bsum[t] = sh[t] - v;       // exclusive block offsets
}

__global__ __launch_bounds__(256) void k_scan3(
    int* __restrict__ rowptr, int* __restrict__ cursor,
    const int* __restrict__ bsum, int N)
{
    int i = blockIdx.x * 256 + threadIdx.x;
    if (i >= N) return;
    int rp = rowptr[i] + bsum[i >> 8];
    rowptr[i] = rp;
    cursor[i] = rp;
}

__global__ __launch_bounds__(256) void k_scatter(
    const int* __restrict__ ei, int* __restrict__ cursor,
    int* __restrict__ csr_eid, int* __restrict__ csr_src, int E)
{
    int e = blockIdx.x * 256 + threadIdx.x;
    if (e >= E) return;
    int s = ei[e];
    int d = ei[E + e];
    int slot = atomicAdd(&cursor[d], 1);
    csr_eid[slot] = e;
    csr_src[slot] = s;
}

// ============ conv1 aggregation: agg1[n,c] = sum_e relu(x[src,c]+ea@We1+be1) ==
// 8 nodes per block of 256; half-wave (32 lanes) per node, lane = channel.
__global__ __launch_bounds__(256) void k_agg1(
    const float* __restrict__ x, const float* __restrict__ ea,
    const float* __restrict__ We, const float* __restrict__ be,
    const int* __restrict__ rowptr, const int* __restrict__ deg,
    const int* __restrict__ csr_eid, const int* __restrict__ csr_src,
    float* __restrict__ agg, int N)
{
    int n = blockIdx.x * 8 + (threadIdx.x >> 5);
    int c = threadIdx.x & 31;
    if (n >= N) return;
    float w[16];
    #pragma unroll
    for (int k = 0; k < 16; ++k) w[k] = We[k * 32 + c];
    const float bias = be[c];
    int start = rowptr[n];
    int dg = deg[n];
    float acc = 0.f;
    for (int j = 0; j < dg; ++j) {
        int eid = csr_eid[start + j];
        int s   = csr_src[start + j];
        const float4* eap = reinterpret_cast<const float4*>(ea) + (size_t)eid * 4;
        float4 e0 = eap[0], e1 = eap[1], e2 = eap[2], e3 = eap[3];
        float m = bias;
        m = fmaf(e0.x, w[0], m);  m = fmaf(e0.y, w[1], m);
        m = fmaf(e0.z, w[2], m);  m = fmaf(e0.w, w[3], m);
        m = fmaf(e1.x, w[4], m);  m = fmaf(e1.y, w[5], m);
        m = fmaf(e1.z, w[6], m);  m = fmaf(e1.w, w[7], m);
        m = fmaf(e2.x, w[8], m);  m = fmaf(e2.y, w[9], m);
        m = fmaf(e2.z, w[10], m); m = fmaf(e2.w, w[11], m);
        m = fmaf(e3.x, w[12], m); m = fmaf(e3.y, w[13], m);
        m = fmaf(e3.z, w[14], m); m = fmaf(e3.w, w[15], m);
        m += x[(size_t)s * 32 + c];
        acc += (m > 0.f ? m : 0.f);
    }
    agg[(size_t)n * 32 + c] = acc;
}

// ============ conv2 aggregation: 64 channels, one wave per node ==============
__global__ __launch_bounds__(256) void k_agg2(
    const float* __restrict__ h1, const float* __restrict__ ea,
    const float* __restrict__ We, const float* __restrict__ be,
    const int* __restrict__ rowptr, const int* __restrict__ deg,
    const int* __restrict__ csr_eid, const int* __restrict__ csr_src,
    float* __restrict__ agg, int N)
{
    int n = blockIdx.x * 4 + (threadIdx.x >> 6);
    int c = threadIdx.x & 63;
    if (n >= N) return;
    float w[16];
    #pragma unroll
    for (int k = 0; k < 16; ++k) w[k] = We[k * 64 + c];
    const float bias = be[c];
    int start = rowptr[n];
    int dg = deg[n];
    float acc = 0.f;
    for (int j = 0; j < dg; ++j) {
        int eid = csr_eid[start + j];
        int s   = csr_src[start + j];
        const float4* eap = reinterpret_cast<const float4*>(ea) + (size_t)eid * 4;
        float4 e0 = eap[0], e1 = eap[1], e2 = eap[2], e3 = eap[3];
        float m = bias;
        m = fmaf(e0.x, w[0], m);  m = fmaf(e0.y, w[1], m);
        m = fmaf(e0.z, w[2], m);  m = fmaf(e0.w, w[3], m);
        m = fmaf(e1.x, w[4], m);  m = fmaf(e1.y, w[5], m);
        m = fmaf(e1.z, w[6], m);  m = fmaf(e1.w, w[7], m);
        m = fmaf(e2.x, w[8], m);  m = fmaf(e2.y, w[9], m);
        m = fmaf(e2.z, w[10], m); m = fmaf(e2.w, w[11], m);
        m = fmaf(e3.x, w[12], m); m = fmaf(e3.y, w[13], m);
        m = fmaf(e3.z, w[14], m); m = fmaf(e3.w, w[15], m);
        m += h1[(size_t)s * 64 + c];
        acc += (m > 0.f ? m : 0.f);
    }
    agg[(size_t)n * 64 + c] = acc;
}

// ---------------- conv1 node nn: h1 = lrelu( lrelu((x+agg1)@W1a+b1a)@W1b + b1b )
__global__ __launch_bounds__(256) void k_mlp1(
    const float* __restrict__ x, const float* __restrict__ agg1,
    const float* __restrict__ W1a, const float* __restrict__ b1a,
    const float* __restrict__ W1b, const float* __restrict__ b1b,
    float* __restrict__ h1, int N)
{
    int n = blockIdx.x * 256 + threadIdx.x;
    if (n >= N) return;
    float h[32];
    {
        const float4* xp = reinterpret_cast<const float4*>(x) + (size_t)n * 8;
        const float4* ap = reinterpret_cast<const float4*>(agg1) + (size_t)n * 8;
        #pragma unroll
        for (int q = 0; q < 8; ++q) {
            float4 a = xp[q], b = ap[q];
            h[4*q+0]=a.x+b.x; h[4*q+1]=a.y+b.y; h[4*q+2]=a.z+b.z; h[4*q+3]=a.w+b.w;
        }
    }
    float t[32];
    #pragma unroll
    for (int c = 0; c < 32; ++c) {
        float v = b1a[c];
        #pragma unroll
        for (int k = 0; k < 32; ++k) v = fmaf(h[k], W1a[k*32+c], v);
        t[c] = lrelu(v);
    }
    const float4* W1b4 = reinterpret_cast<const float4*>(W1b);
    const float4* b1b4 = reinterpret_cast<const float4*>(b1b);
    float4* op = reinterpret_cast<float4*>(h1) + (size_t)n * 16;
    for (int cq = 0; cq < 16; ++cq) {
        float4 bv = b1b4[cq];
        float a0 = bv.x, a1 = bv.y, a2 = bv.z, a3 = bv.w;
        #pragma unroll
        for (int k = 0; k < 32; ++k) {
            float4 w = W1b4[k*16 + cq];
            a0 = fmaf(t[k], w.x, a0); a1 = fmaf(t[k], w.y, a1);
            a2 = fmaf(t[k], w.z, a2); a3 = fmaf(t[k], w.w, a3);
        }
        float4 o; o.x = lrelu(a0); o.y = lrelu(a1); o.z = lrelu(a2); o.w = lrelu(a3);
        op[cq] = o;
    }
}

// ---------------- conv2 nn layer 1: t = lrelu((h1+agg2)@W2a + b2a)  [N,128] ----
__global__ __launch_bounds__(256) void k_mlp2a(
    const float* __restrict__ h1, const float* __restrict__ agg2,
    const float* __restrict__ W2a, const float* __restrict__ b2a,
    float* __restrict__ t, int N)
{
    int n = blockIdx.x * 256 + threadIdx.x;
    if (n >= N) return;
    float h[64];
    {
        const float4* xp = reinterpret_cast<const float4*>(h1) + (size_t)n * 16;
        const float4* ap = reinterpret_cast<const float4*>(agg2) + (size_t)n * 16;
        #pragma unroll
        for (int q = 0; q < 16; ++q) {
            float4 a = xp[q], b = ap[q];
            h[4*q+0]=a.x+b.x; h[4*q+1]=a.y+b.y; h[4*q+2]=a.z+b.z; h[4*q+3]=a.w+b.w;
        }
    }
    const float4* W4 = reinterpret_cast<const float4*>(W2a);
    const float4* b4 = reinterpret_cast<const float4*>(b2a);
    float4* op = reinterpret_cast<float4*>(t) + (size_t)n * 32;
    for (int cq = 0; cq < 32; ++cq) {
        float4 bv = b4[cq];
        float a0 = bv.x, a1 = bv.y, a2 = bv.z, a3 = bv.w;
        #pragma unroll
        for (int k = 0; k < 64; ++k) {
            float4 w = W4[k*32 + cq];
            a0 = fmaf(h[k], w.x, a0); a1 = fmaf(h[k], w.y, a1);
            a2 = fmaf(h[k], w.z, a2); a3 = fmaf(h[k], w.w, a3);
        }
        float4 o; o.x = lrelu(a0); o.y = lrelu(a1); o.z = lrelu(a2); o.w = lrelu(a3);
        op[cq] = o;
    }
}

// ---------------- conv2 nn layer 2: h2 = lrelu(t@W2b + b2b)  [N,256] -----------
__global__ __launch_bounds__(256) void k_mlp2b(
    const float* __restrict__ t, const float* __restrict__ W2b,
    const float* __restrict__ b2b, float* __restrict__ h2, int N)
{
    int n = blockIdx.x * 256 + threadIdx.x;
    if (n >= N) return;
    float tv[128];
    {
        const float4* p = reinterpret_cast<const float4*>(t) + (size_t)n * 32;
        #pragma unroll
        for (int q = 0; q < 32; ++q) {
            float4 v = p[q];
            tv[4*q+0]=v.x; tv[4*q+1]=v.y; tv[4*q+2]=v.z; tv[4*q+3]=v.w;
        }
    }
    const float4* W4 = reinterpret_cast<const float4*>(W2b);
    const float4* b4 = reinterpret_cast<const float4*>(b2b);
    float4* op = reinterpret_cast<float4*>(h2) + (size_t)n * 64;
    for (int cq = 0; cq < 64; ++cq) {
        float4 bv = b4[cq];
        float a0 = bv.x, a1 = bv.y, a2 = bv.z, a3 = bv.w;
        #pragma unroll
        for (int k = 0; k < 128; ++k) {
            float4 w = W4[k*64 + cq];
            a0 = fmaf(tv[k], w.x, a0); a1 = fmaf(tv[k], w.y, a1);
            a2 = fmaf(tv[k], w.z, a2); a3 = fmaf(tv[k], w.w, a3);
        }
        float4 o; o.x = lrelu(a0); o.y = lrelu(a1); o.z = lrelu(a2); o.w = lrelu(a3);
        op[cq] = o;
    }
}

// ---------------- global_add_pool over sorted batch ids ------------------------
__global__ __launch_bounds__(256) void k_pool(
    const float* __restrict__ h2, const int* __restrict__ batch,
    float* __restrict__ g, int N)
{
    int c = threadIdx.x;
    int n0 = blockIdx.x * 128;
    int nend = n0 + 128; if (nend > N) nend = N;
    float acc = 0.f;
    int cur = batch[n0];
    for (int n = n0; n < nend; ++n) {
        int b = batch[n];
        if (b != cur) {
            atomicAdd(&g[(size_t)cur*256 + c], acc);
            acc = 0.f; cur = b;
        }
        acc += h2[(size_t)n*256 + c];
    }
    atomicAdd(&g[(size_t)cur*256 + c], acc);
}

// ---------------- head MLP: one block per graph --------------------------------
__global__ __launch_bounds__(256) void k_head(
    const float* __restrict__ g,
    const float* __restrict__ Wf0, const float* __restrict__ bf0,
    const float* __restrict__ Wf1, const float* __restrict__ bf1,
    const float* __restrict__ Wf2, const float* __restrict__ bf2,
    const float* __restrict__ Wr,  const float* __restrict__ br,
    float* __restrict__ out)
{
    __shared__ float buf[256];
    __shared__ float t0[128];
    __shared__ float t1[64];
    __shared__ float t2[32];
    int gid = blockIdx.x, tid = threadIdx.x;
    buf[tid] = g[(size_t)gid*256 + tid];
    __syncthreads();
    if (tid < 128) {
        float acc = bf0[tid];
        for (int k = 0; k < 256; ++k) acc = fmaf(buf[k], Wf0[k*128 + tid], acc);
        t0[tid] = lrelu(acc);
    }
    __syncthreads();
    if (tid < 64) {
        float acc = bf1[tid];
        for (int k = 0; k < 128; ++k) acc = fmaf(t0[k], Wf1[k*64 + tid], acc);
        t1[tid] = lrelu(acc);
    }
    __syncthreads();
    if (tid < 32) {
        float acc = bf2[tid];
        for (int k = 0; k < 64; ++k) acc = fmaf(t1[k], Wf2[k*32 + tid], acc);
        t2[tid] = lrelu(acc);
    }
    __syncthreads();
    if (tid == 0) {
        float acc = br[0];
        for (int k = 0; k < 32; ++k) acc = fmaf(t2[k], Wr[k], acc);
        out[gid] = acc;
    }
}

extern "C" void kernel_launch(void* const* d_in, const int* in_sizes, int n_in,
                              void* d_out, int out_size, void* d_ws, size_t ws_size,
                              hipStream_t stream)
{
    const float* x     = (const float*)d_in[0];
    const int*   ei    = (const int*)d_in[1];
    const float* ea    = (const float*)d_in[2];
    const int*   batch = (const int*)d_in[3];
    const float* We1=(const float*)d_in[4],  *be1=(const float*)d_in[5];
    const float* W1a=(const float*)d_in[6],  *b1a=(const float*)d_in[7];
    const float* W1b=(const float*)d_in[8],  *b1b=(const float*)d_in[9];
    const float* We2=(const float*)d_in[10], *be2=(const float*)d_in[11];
    const float* W2a=(const float*)d_in[12], *b2a=(const float*)d_in[13];
    const float* W2b=(const float*)d_in[14], *b2b=(const float*)d_in[15];
    const float* Wf0=(const float*)d_in[16], *bf0=(const float*)d_in[17];
    const float* Wf1=(const float*)d_in[18], *bf1=(const float*)d_in[19];
    const float* Wf2=(const float*)d_in[20], *bf2=(const float*)d_in[21];
    const float* Wr =(const float*)d_in[22], *br =(const float*)d_in[23];

    const int N = in_sizes[0] / 32;
    const int E = in_sizes[1] / 2;
    const int G = out_size;
    const int nb = (N + 255) / 256;

    // ---- workspace layout ----
    // zeroed prefix: [deg N ints][gbuf G*256 floats]
    // then: rowptr, cursor, bsum(512), csr_eid(E), csr_src(E)  (ints)
    //       agg1 N*32, agg2 N*64, h1 N*64, tbuf N*128, h2 N*256 (floats)
    char* p = (char*)d_ws;
    int*   deg     = (int*)p;                 p += (size_t)N * 4;
    float* gbuf    = (float*)p;               p += (size_t)G * 256 * 4;
    size_t zero_bytes = (size_t)(p - (char*)d_ws);
    int*   rowptr  = (int*)p;                 p += (size_t)N * 4;
    int*   cursor  = (int*)p;                 p += (size_t)N * 4;
    int*   bsum    = (int*)p;                 p += 512 * 4;
    int*   csr_eid = (int*)p;                 p += (size_t)E * 4;
    int*   csr_src = (int*)p;                 p += (size_t)E * 4;
    float* agg1    = (float*)p;               p += (size_t)N * 32 * 4;
    float* agg2    = (float*)p;               p += (size_t)N * 64 * 4;
    float* h1      = (float*)p;               p += (size_t)N * 64 * 4;
    float* tbuf    = (float*)p;               p += (size_t)N * 128 * 4;
    float* h2      = (float*)p;               p += (size_t)N * 256 * 4;

    hipMemsetAsync(d_ws, 0, zero_bytes, stream);

    int eb = (E + 255) / 256;

    // CSR build
    k_hist   <<<eb, 256, 0, stream>>>(ei, deg, E);
    k_scan1  <<<nb, 256, 0, stream>>>(deg, rowptr, bsum, N);
    k_scan2  <<<1, 512, 0, stream>>>(bsum, nb);
    k_scan3  <<<nb, 256, 0, stream>>>(rowptr, cursor, bsum, N);
    k_scatter<<<eb, 256, 0, stream>>>(ei, cursor, csr_eid, csr_src, E);

    // conv1
    k_agg1<<<(N + 7) / 8, 256, 0, stream>>>(x, ea, We1, be1, rowptr, deg,
                                            csr_eid, csr_src, agg1, N);
    k_mlp1<<<nb, 256, 0, stream>>>(x, agg1, W1a, b1a, W1b, b1b, h1, N);

    // conv2
    k_agg2<<<(N + 3) / 4, 256, 0, stream>>>(h1, ea, We2, be2, rowptr, deg,
                                            csr_eid, csr_src, agg2, N);
    k_mlp2a<<<nb, 256, 0, stream>>>(h1, agg2, W2a, b2a, tbuf, N);
    k_mlp2b<<<nb, 256, 0, stream>>>(tbuf, W2b, b2b, h2, N);

    // pool + head
    k_pool<<<(N + 127) / 128, 256, 0, stream>>>(h2, batch, gbuf, N);
    k_head<<<G, 256, 0, stream>>>(gbuf, Wf0, bf0, Wf1, bf1, Wf2, bf2, Wr, br,
                                  (float*)d_out);
}

// Round 3
// 1059.104 us; speedup vs baseline: 8.1418x; 1.2596x over previous
//
#include <hip/hip_runtime.h>

__device__ __forceinline__ float lrelu(float v){ return v > 0.f ? v : 0.01f*v; }

// ================= CSR build =================================================
__global__ __launch_bounds__(256) void k_hist(
    const int* __restrict__ ei, int* __restrict__ deg, int E)
{
    int e = blockIdx.x * 256 + threadIdx.x;
    if (e >= E) return;
    atomicAdd(&deg[ei[E + e]], 1);
}

__global__ __launch_bounds__(256) void k_scan1(
    const int* __restrict__ deg, int* __restrict__ rowptr,
    int* __restrict__ bsum, int N)
{
    __shared__ int sh[256];
    int t = threadIdx.x;
    int i = blockIdx.x * 256 + t;
    int v = (i < N) ? deg[i] : 0;
    sh[t] = v;
    __syncthreads();
    #pragma unroll
    for (int off = 1; off < 256; off <<= 1) {
        int add = (t >= off) ? sh[t - off] : 0;
        __syncthreads();
        sh[t] += add;
        __syncthreads();
    }
    if (i < N) rowptr[i] = sh[t] - v;      // exclusive within block
    if (t == 255) bsum[blockIdx.x] = sh[t];
}

__global__ __launch_bounds__(512) void k_scan2(int* __restrict__ bsum, int nb)
{
    __shared__ int sh[512];
    int t = threadIdx.x;
    int v = (t < nb) ? bsum[t] : 0;
    sh[t] = v;
    __syncthreads();
    #pragma unroll
    for (int off = 1; off < 512; off <<= 1) {
        int add = (t >= off) ? sh[t - off] : 0;
        __syncthreads();
        sh[t] += add;
        __syncthreads();
    }
    if (t < nb) bsum[t] = sh[t] - v;       // exclusive block offsets
}

__global__ __launch_bounds__(256) void k_scan3(
    int* __restrict__ rowptr, int* __restrict__ cursor,
    const int* __restrict__ bsum, int N)
{
    int i = blockIdx.x * 256 + threadIdx.x;
    if (i >= N) return;
    int rp = rowptr[i] + bsum[i >> 8];
    rowptr[i] = rp;
    cursor[i] = rp;
}

__global__ __launch_bounds__(256) void k_scatter(
    const int* __restrict__ ei, int* __restrict__ cursor,
    int* __restrict__ csr_eid, int* __restrict__ csr_src, int E)
{
    int e = blockIdx.x * 256 + threadIdx.x;
    if (e >= E) return;
    int s = ei[e];
    int d = ei[E + e];
    int slot = atomicAdd(&cursor[d], 1);
    csr_eid[slot] = e;
    csr_src[slot] = s;
}

// ============ conv1 aggregation ==============================================
__global__ __launch_bounds__(256) void k_agg1(
    const float* __restrict__ x, const float* __restrict__ ea,
    const float* __restrict__ We, const float* __restrict__ be,
    const int* __restrict__ rowptr, const int* __restrict__ deg,
    const int* __restrict__ csr_eid, const int* __restrict__ csr_src,
    float* __restrict__ agg, int N)
{
    int n = blockIdx.x * 8 + (threadIdx.x >> 5);
    int c = threadIdx.x & 31;
    if (n >= N) return;
    float w[16];
    #pragma unroll
    for (int k = 0; k < 16; ++k) w[k] = We[k * 32 + c];
    const float bias = be[c];
    int start = rowptr[n];
    int dg = deg[n];
    float acc = 0.f;
    for (int j = 0; j < dg; ++j) {
        int eid = csr_eid[start + j];
        int s   = csr_src[start + j];
        const float4* eap = reinterpret_cast<const float4*>(ea) + (size_t)eid * 4;
        float4 e0 = eap[0], e1 = eap[1], e2 = eap[2], e3 = eap[3];
        float m = bias;
        m = fmaf(e0.x, w[0], m);  m = fmaf(e0.y, w[1], m);
        m = fmaf(e0.z, w[2], m);  m = fmaf(e0.w, w[3], m);
        m = fmaf(e1.x, w[4], m);  m = fmaf(e1.y, w[5], m);
        m = fmaf(e1.z, w[6], m);  m = fmaf(e1.w, w[7], m);
        m = fmaf(e2.x, w[8], m);  m = fmaf(e2.y, w[9], m);
        m = fmaf(e2.z, w[10], m); m = fmaf(e2.w, w[11], m);
        m = fmaf(e3.x, w[12], m); m = fmaf(e3.y, w[13], m);
        m = fmaf(e3.z, w[14], m); m = fmaf(e3.w, w[15], m);
        m += x[(size_t)s * 32 + c];
        acc += (m > 0.f ? m : 0.f);
    }
    agg[(size_t)n * 32 + c] = acc;
}

// ============ conv2 aggregation ==============================================
__global__ __launch_bounds__(256) void k_agg2(
    const float* __restrict__ h1, const float* __restrict__ ea,
    const float* __restrict__ We, const float* __restrict__ be,
    const int* __restrict__ rowptr, const int* __restrict__ deg,
    const int* __restrict__ csr_eid, const int* __restrict__ csr_src,
    float* __restrict__ agg, int N)
{
    int n = blockIdx.x * 4 + (threadIdx.x >> 6);
    int c = threadIdx.x & 63;
    if (n >= N) return;
    float w[16];
    #pragma unroll
    for (int k = 0; k < 16; ++k) w[k] = We[k * 64 + c];
    const float bias = be[c];
    int start = rowptr[n];
    int dg = deg[n];
    float acc = 0.f;
    for (int j = 0; j < dg; ++j) {
        int eid = csr_eid[start + j];
        int s   = csr_src[start + j];
        const float4* eap = reinterpret_cast<const float4*>(ea) + (size_t)eid * 4;
        float4 e0 = eap[0], e1 = eap[1], e2 = eap[2], e3 = eap[3];
        float m = bias;
        m = fmaf(e0.x, w[0], m);  m = fmaf(e0.y, w[1], m);
        m = fmaf(e0.z, w[2], m);  m = fmaf(e0.w, w[3], m);
        m = fmaf(e1.x, w[4], m);  m = fmaf(e1.y, w[5], m);
        m = fmaf(e1.z, w[6], m);  m = fmaf(e1.w, w[7], m);
        m = fmaf(e2.x, w[8], m);  m = fmaf(e2.y, w[9], m);
        m = fmaf(e2.z, w[10], m); m = fmaf(e2.w, w[11], m);
        m = fmaf(e3.x, w[12], m); m = fmaf(e3.y, w[13], m);
        m = fmaf(e3.z, w[14], m); m = fmaf(e3.w, w[15], m);
        m += h1[(size_t)s * 64 + c];
        acc += (m > 0.f ? m : 0.f);
    }
    agg[(size_t)n * 64 + c] = acc;
}

// ============ conv1 node nn, fused both layers ===============================
// 64 rows/block. hs = (x+agg1) [64x32] in LDS, ts [64x32] in LDS, out h1 [64x64].
__global__ __launch_bounds__(256) void k_mlp1(
    const float* __restrict__ x, const float* __restrict__ agg1,
    const float* __restrict__ W1a, const float* __restrict__ b1a,
    const float* __restrict__ W1b, const float* __restrict__ b1b,
    float* __restrict__ h1, int N)
{
    __shared__ float hs[64][33];
    __shared__ float ts[64][33];
    const int tid = threadIdx.x;
    const int n0 = blockIdx.x * 64;
    const int row = tid & 63;
    const int grp = __builtin_amdgcn_readfirstlane(tid >> 6);   // wave-uniform

    // stage hs: thread stages 8 floats: row r = tid>>2, cols (tid&3)*8 .. +8
    {
        int r = tid >> 2, c = (tid & 3) * 8;
        int g = n0 + r;
        if (g < N) {
            const float4* xp = reinterpret_cast<const float4*>(x) + (size_t)g*8 + (c>>2);
            const float4* ap = reinterpret_cast<const float4*>(agg1) + (size_t)g*8 + (c>>2);
            #pragma unroll
            for (int q = 0; q < 2; ++q) {
                float4 a = xp[q], b = ap[q];
                hs[r][c+4*q+0]=a.x+b.x; hs[r][c+4*q+1]=a.y+b.y;
                hs[r][c+4*q+2]=a.z+b.z; hs[r][c+4*q+3]=a.w+b.w;
            }
        } else {
            #pragma unroll
            for (int q = 0; q < 8; ++q) hs[r][c+q] = 0.f;
        }
    }
    __syncthreads();

    // phase 1: ts[row][8*grp .. +8] = lrelu(hs[row] @ W1a + b1a)
    {
        const int c0 = grp * 8;
        float acc[8];
        #pragma unroll
        for (int i = 0; i < 8; ++i) acc[i] = b1a[c0 + i];
        for (int k = 0; k < 32; ++k) {
            float hv = hs[row][k];
            const float* w = W1a + k*32 + c0;
            #pragma unroll
            for (int i = 0; i < 8; ++i) acc[i] = fmaf(hv, w[i], acc[i]);
        }
        #pragma unroll
        for (int i = 0; i < 8; ++i) ts[row][c0 + i] = lrelu(acc[i]);
    }
    __syncthreads();

    // phase 2: h1[row][16*grp .. +16] = lrelu(ts[row] @ W1b + b1b)
    {
        const int c0 = grp * 16;
        float acc[16];
        #pragma unroll
        for (int i = 0; i < 16; ++i) acc[i] = b1b[c0 + i];
        for (int k = 0; k < 32; ++k) {
            float tv = ts[row][k];
            const float* w = W1b + k*64 + c0;
            #pragma unroll
            for (int i = 0; i < 16; ++i) acc[i] = fmaf(tv, w[i], acc[i]);
        }
        int g = n0 + row;
        if (g < N) {
            float4* op = reinterpret_cast<float4*>(h1) + (size_t)g*16 + (c0>>2);
            #pragma unroll
            for (int q = 0; q < 4; ++q) {
                float4 o;
                o.x = lrelu(acc[4*q+0]); o.y = lrelu(acc[4*q+1]);
                o.z = lrelu(acc[4*q+2]); o.w = lrelu(acc[4*q+3]);
                op[q] = o;
            }
        }
    }
}

// ============ conv2 node nn, fused both layers ===============================
// 64 rows/block. hs = (h1+agg2) [64x64], ts [64x128] in LDS, out h2 [64x256].
__global__ __launch_bounds__(256) void k_mlp2(
    const float* __restrict__ h1, const float* __restrict__ agg2,
    const float* __restrict__ W2a, const float* __restrict__ b2a,
    const float* __restrict__ W2b, const float* __restrict__ b2b,
    float* __restrict__ h2, int N)
{
    __shared__ float hs[64][65];
    __shared__ float ts[64][129];
    const int tid = threadIdx.x;
    const int n0 = blockIdx.x * 64;
    const int row = tid & 63;
    const int grp = __builtin_amdgcn_readfirstlane(tid >> 6);   // wave-uniform

    // stage hs: thread stages 16 floats: row r = tid>>2, cols (tid&3)*16 .. +16
    {
        int r = tid >> 2, c = (tid & 3) * 16;
        int g = n0 + r;
        if (g < N) {
            const float4* xp = reinterpret_cast<const float4*>(h1) + (size_t)g*16 + (c>>2);
            const float4* ap = reinterpret_cast<const float4*>(agg2) + (size_t)g*16 + (c>>2);
            #pragma unroll
            for (int q = 0; q < 4; ++q) {
                float4 a = xp[q], b = ap[q];
                hs[r][c+4*q+0]=a.x+b.x; hs[r][c+4*q+1]=a.y+b.y;
                hs[r][c+4*q+2]=a.z+b.z; hs[r][c+4*q+3]=a.w+b.w;
            }
        } else {
            #pragma unroll
            for (int q = 0; q < 16; ++q) hs[r][c+q] = 0.f;
        }
    }
    __syncthreads();

    // phase 1: ts[row][32*grp .. +32] = lrelu(hs[row] @ W2a + b2a)
    {
        const int c0 = grp * 32;
        float acc[32];
        #pragma unroll
        for (int i = 0; i < 32; ++i) acc[i] = b2a[c0 + i];
        for (int k = 0; k < 64; ++k) {
            float hv = hs[row][k];
            const float* w = W2a + k*128 + c0;
            #pragma unroll
            for (int i = 0; i < 32; ++i) acc[i] = fmaf(hv, w[i], acc[i]);
        }
        #pragma unroll
        for (int i = 0; i < 32; ++i) ts[row][c0 + i] = lrelu(acc[i]);
    }
    __syncthreads();

    // phase 2: h2[row][64*grp .. +64] = lrelu(ts[row] @ W2b + b2b)
    {
        const int c0 = grp * 64;
        float acc[64];
        #pragma unroll
        for (int i = 0; i < 64; ++i) acc[i] = b2b[c0 + i];
        for (int k = 0; k < 128; ++k) {
            float tv = ts[row][k];
            const float* w = W2b + k*256 + c0;
            #pragma unroll
            for (int i = 0; i < 64; ++i) acc[i] = fmaf(tv, w[i], acc[i]);
        }
        int g = n0 + row;
        if (g < N) {
            float4* op = reinterpret_cast<float4*>(h2) + (size_t)g*64 + (c0>>2);
            #pragma unroll
            for (int q = 0; q < 16; ++q) {
                float4 o;
                o.x = lrelu(acc[4*q+0]); o.y = lrelu(acc[4*q+1]);
                o.z = lrelu(acc[4*q+2]); o.w = lrelu(acc[4*q+3]);
                op[q] = o;
            }
        }
    }
}

// ---------------- global_add_pool over sorted batch ids ------------------------
__global__ __launch_bounds__(256) void k_pool(
    const float* __restrict__ h2, const int* __restrict__ batch,
    float* __restrict__ g, int N)
{
    int c = threadIdx.x;
    int n0 = blockIdx.x * 128;
    int nend = n0 + 128; if (nend > N) nend = N;
    float acc = 0.f;
    int cur = batch[n0];
    for (int n = n0; n < nend; ++n) {
        int b = batch[n];
        if (b != cur) {
            atomicAdd(&g[(size_t)cur*256 + c], acc);
            acc = 0.f; cur = b;
        }
        acc += h2[(size_t)n*256 + c];
    }
    atomicAdd(&g[(size_t)cur*256 + c], acc);
}

// ---------------- head MLP: one block per graph --------------------------------
__global__ __launch_bounds__(256) void k_head(
    const float* __restrict__ g,
    const float* __restrict__ Wf0, const float* __restrict__ bf0,
    const float* __restrict__ Wf1, const float* __restrict__ bf1,
    const float* __restrict__ Wf2, const float* __restrict__ bf2,
    const float* __restrict__ Wr,  const float* __restrict__ br,
    float* __restrict__ out)
{
    __shared__ float buf[256];
    __shared__ float t0[128];
    __shared__ float t1[64];
    __shared__ float t2[32];
    int gid = blockIdx.x, tid = threadIdx.x;
    buf[tid] = g[(size_t)gid*256 + tid];
    __syncthreads();
    if (tid < 128) {
        float acc = bf0[tid];
        for (int k = 0; k < 256; ++k) acc = fmaf(buf[k], Wf0[k*128 + tid], acc);
        t0[tid] = lrelu(acc);
    }
    __syncthreads();
    if (tid < 64) {
        float acc = bf1[tid];
        for (int k = 0; k < 128; ++k) acc = fmaf(t0[k], Wf1[k*64 + tid], acc);
        t1[tid] = lrelu(acc);
    }
    __syncthreads();
    if (tid < 32) {
        float acc = bf2[tid];
        for (int k = 0; k < 64; ++k) acc = fmaf(t1[k], Wf2[k*32 + tid], acc);
        t2[tid] = lrelu(acc);
    }
    __syncthreads();
    if (tid == 0) {
        float acc = br[0];
        for (int k = 0; k < 32; ++k) acc = fmaf(t2[k], Wr[k], acc);
        out[gid] = acc;
    }
}

extern "C" void kernel_launch(void* const* d_in, const int* in_sizes, int n_in,
                              void* d_out, int out_size, void* d_ws, size_t ws_size,
                              hipStream_t stream)
{
    const float* x     = (const float*)d_in[0];
    const int*   ei    = (const int*)d_in[1];
    const float* ea    = (const float*)d_in[2];
    const int*   batch = (const int*)d_in[3];
    const float* We1=(const float*)d_in[4],  *be1=(const float*)d_in[5];
    const float* W1a=(const float*)d_in[6],  *b1a=(const float*)d_in[7];
    const float* W1b=(const float*)d_in[8],  *b1b=(const float*)d_in[9];
    const float* We2=(const float*)d_in[10], *be2=(const float*)d_in[11];
    const float* W2a=(const float*)d_in[12], *b2a=(const float*)d_in[13];
    const float* W2b=(const float*)d_in[14], *b2b=(const float*)d_in[15];
    const float* Wf0=(const float*)d_in[16], *bf0=(const float*)d_in[17];
    const float* Wf1=(const float*)d_in[18], *bf1=(const float*)d_in[19];
    const float* Wf2=(const float*)d_in[20], *bf2=(const float*)d_in[21];
    const float* Wr =(const float*)d_in[22], *br =(const float*)d_in[23];

    const int N = in_sizes[0] / 32;
    const int E = in_sizes[1] / 2;
    const int G = out_size;
    const int nb = (N + 255) / 256;
    const int nb64 = (N + 63) / 64;

    // ---- workspace layout ----
    char* p = (char*)d_ws;
    int*   deg     = (int*)p;                 p += (size_t)N * 4;
    float* gbuf    = (float*)p;               p += (size_t)G * 256 * 4;
    size_t zero_bytes = (size_t)(p - (char*)d_ws);
    int*   rowptr  = (int*)p;                 p += (size_t)N * 4;
    int*   cursor  = (int*)p;                 p += (size_t)N * 4;
    int*   bsum    = (int*)p;                 p += 512 * 4;
    int*   csr_eid = (int*)p;                 p += (size_t)E * 4;
    int*   csr_src = (int*)p;                 p += (size_t)E * 4;
    float* agg1    = (float*)p;               p += (size_t)N * 32 * 4;
    float* agg2    = (float*)p;               p += (size_t)N * 64 * 4;
    float* h1      = (float*)p;               p += (size_t)N * 64 * 4;
    float* h2      = (float*)p;               p += (size_t)N * 256 * 4;

    hipMemsetAsync(d_ws, 0, zero_bytes, stream);

    int eb = (E + 255) / 256;

    // CSR build
    k_hist   <<<eb, 256, 0, stream>>>(ei, deg, E);
    k_scan1  <<<nb, 256, 0, stream>>>(deg, rowptr, bsum, N);
    k_scan2  <<<1, 512, 0, stream>>>(bsum, nb);
    k_scan3  <<<nb, 256, 0, stream>>>(rowptr, cursor, bsum, N);
    k_scatter<<<eb, 256, 0, stream>>>(ei, cursor, csr_eid, csr_src, E);

    // conv1
    k_agg1<<<(N + 7) / 8, 256, 0, stream>>>(x, ea, We1, be1, rowptr, deg,
                                            csr_eid, csr_src, agg1, N);
    k_mlp1<<<nb64, 256, 0, stream>>>(x, agg1, W1a, b1a, W1b, b1b, h1, N);

    // conv2
    k_agg2<<<(N + 3) / 4, 256, 0, stream>>>(h1, ea, We2, be2, rowptr, deg,
                                            csr_eid, csr_src, agg2, N);
    k_mlp2<<<nb64, 256, 0, stream>>>(h1, agg2, W2a, b2a, W2b, b2b, h2, N);

    // pool + head
    k_pool<<<(N + 127) / 128, 256, 0, stream>>>(h2, batch, gbuf, N);
    k_head<<<G, 256, 0, stream>>>(gbuf, Wf0, bf0, Wf1, bf1, Wf2, bf2, Wr, br,
                                  (float*)d_out);
}

// Round 4
// 1042.817 us; speedup vs baseline: 8.2689x; 1.0156x over previous
//
#include <hip/hip_runtime.h>

__device__ __forceinline__ float lrelu(float v){ return v > 0.f ? v : 0.01f*v; }

// ================= CSR build =================================================
__global__ __launch_bounds__(256) void k_hist(
    const int* __restrict__ ei, int* __restrict__ deg, int E)
{
    int e = blockIdx.x * 256 + threadIdx.x;
    if (e >= E) return;
    atomicAdd(&deg[ei[E + e]], 1);
}

__global__ __launch_bounds__(256) void k_scan1(
    const int* __restrict__ deg, int* __restrict__ rowptr,
    int* __restrict__ bsum, int N)
{
    __shared__ int sh[256];
    int t = threadIdx.x;
    int i = blockIdx.x * 256 + t;
    int v = (i < N) ? deg[i] : 0;
    sh[t] = v;
    __syncthreads();
    #pragma unroll
    for (int off = 1; off < 256; off <<= 1) {
        int add = (t >= off) ? sh[t - off] : 0;
        __syncthreads();
        sh[t] += add;
        __syncthreads();
    }
    if (i < N) rowptr[i] = sh[t] - v;
    if (t == 255) bsum[blockIdx.x] = sh[t];
}

__global__ __launch_bounds__(512) void k_scan2(int* __restrict__ bsum, int nb)
{
    __shared__ int sh[512];
    int t = threadIdx.x;
    int v = (t < nb) ? bsum[t] : 0;
    sh[t] = v;
    __syncthreads();
    #pragma unroll
    for (int off = 1; off < 512; off <<= 1) {
        int add = (t >= off) ? sh[t - off] : 0;
        __syncthreads();
        sh[t] += add;
        __syncthreads();
    }
    if (t < nb) bsum[t] = sh[t] - v;
}

__global__ __launch_bounds__(256) void k_scan3(
    int* __restrict__ rowptr, int* __restrict__ cursor,
    const int* __restrict__ bsum, int N)
{
    int i = blockIdx.x * 256 + threadIdx.x;
    if (i >= N) return;
    int rp = rowptr[i] + bsum[i >> 8];
    rowptr[i] = rp;
    cursor[i] = rp;
}

// packed CSR record: x=eid, y=src, z=dst, w=unused
__global__ __launch_bounds__(256) void k_scatter(
    const int* __restrict__ ei, int* __restrict__ cursor,
    int4* __restrict__ csr, int E)
{
    int e = blockIdx.x * 256 + threadIdx.x;
    if (e >= E) return;
    int s = ei[e];
    int d = ei[E + e];
    int slot = atomicAdd(&cursor[d], 1);
    int4 rec; rec.x = e; rec.y = s; rec.z = d; rec.w = 0;
    csr[slot] = rec;
}

// ============ conv1 aggregation: edge-major, 2 slots/wave-iter ===============
// lane = (half, c): half=(tid>>5)&1 picks slot parity, c=tid&31 = channel.
#define SPW1 256
__global__ __launch_bounds__(256) void k_agg1(
    const float* __restrict__ x, const float* __restrict__ ea,
    const float* __restrict__ We, const float* __restrict__ be,
    const int4* __restrict__ csr, float* __restrict__ agg, int E)
{
    const int tid = threadIdx.x;
    const int c = tid & 31;
    const int half = (tid >> 5) & 1;
    const int wave = __builtin_amdgcn_readfirstlane((blockIdx.x * 256 + tid) >> 6);
    const long s0 = (long)wave * SPW1;
    if (s0 >= E) return;
    const long send = (s0 + SPW1 < (long)E) ? s0 + SPW1 : (long)E;

    float w[16];
    #pragma unroll
    for (int k = 0; k < 16; ++k) w[k] = We[k * 32 + c];
    const float bias = be[c];

    const bool active = (s0 + half) < send;
    int cur = active ? csr[s0 + half].z : 0;
    float acc = 0.f;

    for (int i = 0; i < SPW1 / 2; ++i) {
        long sl = s0 + 2 * i + half;
        if (sl >= send) break;
        int4 rec = csr[sl];
        if (rec.z != cur) {
            atomicAdd(&agg[(size_t)cur * 32 + c], acc);
            acc = 0.f; cur = rec.z;
        }
        const float4* eap = reinterpret_cast<const float4*>(ea) + (size_t)rec.x * 4;
        float4 e0 = eap[0], e1 = eap[1], e2 = eap[2], e3 = eap[3];
        float m = bias;
        m = fmaf(e0.x, w[0], m);  m = fmaf(e0.y, w[1], m);
        m = fmaf(e0.z, w[2], m);  m = fmaf(e0.w, w[3], m);
        m = fmaf(e1.x, w[4], m);  m = fmaf(e1.y, w[5], m);
        m = fmaf(e1.z, w[6], m);  m = fmaf(e1.w, w[7], m);
        m = fmaf(e2.x, w[8], m);  m = fmaf(e2.y, w[9], m);
        m = fmaf(e2.z, w[10], m); m = fmaf(e2.w, w[11], m);
        m = fmaf(e3.x, w[12], m); m = fmaf(e3.y, w[13], m);
        m = fmaf(e3.z, w[14], m); m = fmaf(e3.w, w[15], m);
        m += x[(size_t)rec.y * 32 + c];
        acc += (m > 0.f ? m : 0.f);
    }
    if (active) atomicAdd(&agg[(size_t)cur * 32 + c], acc);
}

// ============ conv2 aggregation: edge-major, wave-uniform slot ===============
// lane = channel c in [0,64); whole wave walks consecutive slots.
#define SPW2 128
__global__ __launch_bounds__(256) void k_agg2(
    const float* __restrict__ h1, const float* __restrict__ ea,
    const float* __restrict__ We, const float* __restrict__ be,
    const int4* __restrict__ csr, float* __restrict__ agg, int E)
{
    const int tid = threadIdx.x;
    const int c = tid & 63;
    const int wave = __builtin_amdgcn_readfirstlane((blockIdx.x * 256 + tid) >> 6);
    const long s0 = (long)wave * SPW2;
    if (s0 >= E) return;
    const long send = (s0 + SPW2 < (long)E) ? s0 + SPW2 : (long)E;

    float w[16];
    #pragma unroll
    for (int k = 0; k < 16; ++k) w[k] = We[k * 64 + c];
    const float bias = be[c];

    int cur = csr[s0].z;     // wave-uniform (s_load)
    float acc = 0.f;

    for (long sl = s0; sl < send; ++sl) {
        int4 rec = csr[sl];  // wave-uniform -> s_load_dwordx4
        if (rec.z != cur) {  // wave-uniform branch
            atomicAdd(&agg[(size_t)cur * 64 + c], acc);
            acc = 0.f; cur = rec.z;
        }
        const float4* eap = reinterpret_cast<const float4*>(ea) + (size_t)rec.x * 4;
        float4 e0 = eap[0], e1 = eap[1], e2 = eap[2], e3 = eap[3];
        float m = bias;
        m = fmaf(e0.x, w[0], m);  m = fmaf(e0.y, w[1], m);
        m = fmaf(e0.z, w[2], m);  m = fmaf(e0.w, w[3], m);
        m = fmaf(e1.x, w[4], m);  m = fmaf(e1.y, w[5], m);
        m = fmaf(e1.z, w[6], m);  m = fmaf(e1.w, w[7], m);
        m = fmaf(e2.x, w[8], m);  m = fmaf(e2.y, w[9], m);
        m = fmaf(e2.z, w[10], m); m = fmaf(e2.w, w[11], m);
        m = fmaf(e3.x, w[12], m); m = fmaf(e3.y, w[13], m);
        m = fmaf(e3.z, w[14], m); m = fmaf(e3.w, w[15], m);
        m += h1[(size_t)rec.y * 64 + c];
        acc += (m > 0.f ? m : 0.f);
    }
    atomicAdd(&agg[(size_t)cur * 64 + c], acc);
}

// ============ conv1 node nn, fused both layers ===============================
__global__ __launch_bounds__(256) void k_mlp1(
    const float* __restrict__ x, const float* __restrict__ agg1,
    const float* __restrict__ W1a, const float* __restrict__ b1a,
    const float* __restrict__ W1b, const float* __restrict__ b1b,
    float* __restrict__ h1, int N)
{
    __shared__ float hs[64][33];
    __shared__ float ts[64][33];
    const int tid = threadIdx.x;
    const int n0 = blockIdx.x * 64;
    const int row = tid & 63;
    const int grp = __builtin_amdgcn_readfirstlane(tid >> 6);

    {
        int r = tid >> 2, c = (tid & 3) * 8;
        int g = n0 + r;
        if (g < N) {
            const float4* xp = reinterpret_cast<const float4*>(x) + (size_t)g*8 + (c>>2);
            const float4* ap = reinterpret_cast<const float4*>(agg1) + (size_t)g*8 + (c>>2);
            #pragma unroll
            for (int q = 0; q < 2; ++q) {
                float4 a = xp[q], b = ap[q];
                hs[r][c+4*q+0]=a.x+b.x; hs[r][c+4*q+1]=a.y+b.y;
                hs[r][c+4*q+2]=a.z+b.z; hs[r][c+4*q+3]=a.w+b.w;
            }
        } else {
            #pragma unroll
            for (int q = 0; q < 8; ++q) hs[r][c+q] = 0.f;
        }
    }
    __syncthreads();

    {
        const int c0 = grp * 8;
        float acc[8];
        #pragma unroll
        for (int i = 0; i < 8; ++i) acc[i] = b1a[c0 + i];
        for (int k = 0; k < 32; ++k) {
            float hv = hs[row][k];
            const float* w = W1a + k*32 + c0;
            #pragma unroll
            for (int i = 0; i < 8; ++i) acc[i] = fmaf(hv, w[i], acc[i]);
        }
        #pragma unroll
        for (int i = 0; i < 8; ++i) ts[row][c0 + i] = lrelu(acc[i]);
    }
    __syncthreads();

    {
        const int c0 = grp * 16;
        float acc[16];
        #pragma unroll
        for (int i = 0; i < 16; ++i) acc[i] = b1b[c0 + i];
        for (int k = 0; k < 32; ++k) {
            float tv = ts[row][k];
            const float* w = W1b + k*64 + c0;
            #pragma unroll
            for (int i = 0; i < 16; ++i) acc[i] = fmaf(tv, w[i], acc[i]);
        }
        int g = n0 + row;
        if (g < N) {
            float4* op = reinterpret_cast<float4*>(h1) + (size_t)g*16 + (c0>>2);
            #pragma unroll
            for (int q = 0; q < 4; ++q) {
                float4 o;
                o.x = lrelu(acc[4*q+0]); o.y = lrelu(acc[4*q+1]);
                o.z = lrelu(acc[4*q+2]); o.w = lrelu(acc[4*q+3]);
                op[q] = o;
            }
        }
    }
}

// ============ conv2 node nn, fused both layers ===============================
__global__ __launch_bounds__(256) void k_mlp2(
    const float* __restrict__ h1, const float* __restrict__ agg2,
    const float* __restrict__ W2a, const float* __restrict__ b2a,
    const float* __restrict__ W2b, const float* __restrict__ b2b,
    float* __restrict__ h2, int N)
{
    __shared__ float hs[64][65];
    __shared__ float ts[64][129];
    const int tid = threadIdx.x;
    const int n0 = blockIdx.x * 64;
    const int row = tid & 63;
    const int grp = __builtin_amdgcn_readfirstlane(tid >> 6);

    {
        int r = tid >> 2, c = (tid & 3) * 16;
        int g = n0 + r;
        if (g < N) {
            const float4* xp = reinterpret_cast<const float4*>(h1) + (size_t)g*16 + (c>>2);
            const float4* ap = reinterpret_cast<const float4*>(agg2) + (size_t)g*16 + (c>>2);
            #pragma unroll
            for (int q = 0; q < 4; ++q) {
                float4 a = xp[q], b = ap[q];
                hs[r][c+4*q+0]=a.x+b.x; hs[r][c+4*q+1]=a.y+b.y;
                hs[r][c+4*q+2]=a.z+b.z; hs[r][c+4*q+3]=a.w+b.w;
            }
        } else {
            #pragma unroll
            for (int q = 0; q < 16; ++q) hs[r][c+q] = 0.f;
        }
    }
    __syncthreads();

    {
        const int c0 = grp * 32;
        float acc[32];
        #pragma unroll
        for (int i = 0; i < 32; ++i) acc[i] = b2a[c0 + i];
        for (int k = 0; k < 64; ++k) {
            float hv = hs[row][k];
            const float* w = W2a + k*128 + c0;
            #pragma unroll
            for (int i = 0; i < 32; ++i) acc[i] = fmaf(hv, w[i], acc[i]);
        }
        #pragma unroll
        for (int i = 0; i < 32; ++i) ts[row][c0 + i] = lrelu(acc[i]);
    }
    __syncthreads();

    {
        const int c0 = grp * 64;
        float acc[64];
        #pragma unroll
        for (int i = 0; i < 64; ++i) acc[i] = b2b[c0 + i];
        for (int k = 0; k < 128; ++k) {
            float tv = ts[row][k];
            const float* w = W2b + k*256 + c0;
            #pragma unroll
            for (int i = 0; i < 64; ++i) acc[i] = fmaf(tv, w[i], acc[i]);
        }
        int g = n0 + row;
        if (g < N) {
            float4* op = reinterpret_cast<float4*>(h2) + (size_t)g*64 + (c0>>2);
            #pragma unroll
            for (int q = 0; q < 16; ++q) {
                float4 o;
                o.x = lrelu(acc[4*q+0]); o.y = lrelu(acc[4*q+1]);
                o.z = lrelu(acc[4*q+2]); o.w = lrelu(acc[4*q+3]);
                op[q] = o;
            }
        }
    }
}

// ---------------- global_add_pool over sorted batch ids ------------------------
__global__ __launch_bounds__(256) void k_pool(
    const float* __restrict__ h2, const int* __restrict__ batch,
    float* __restrict__ g, int N)
{
    int c = threadIdx.x;
    int n0 = blockIdx.x * 128;
    int nend = n0 + 128; if (nend > N) nend = N;
    float acc = 0.f;
    int cur = batch[n0];
    for (int n = n0; n < nend; ++n) {
        int b = batch[n];
        if (b != cur) {
            atomicAdd(&g[(size_t)cur*256 + c], acc);
            acc = 0.f; cur = b;
        }
        acc += h2[(size_t)n*256 + c];
    }
    atomicAdd(&g[(size_t)cur*256 + c], acc);
}

// ---------------- head MLP -----------------------------------------------------
__global__ __launch_bounds__(256) void k_head(
    const float* __restrict__ g,
    const float* __restrict__ Wf0, const float* __restrict__ bf0,
    const float* __restrict__ Wf1, const float* __restrict__ bf1,
    const float* __restrict__ Wf2, const float* __restrict__ bf2,
    const float* __restrict__ Wr,  const float* __restrict__ br,
    float* __restrict__ out)
{
    __shared__ float buf[256];
    __shared__ float t0[128];
    __shared__ float t1[64];
    __shared__ float t2[32];
    int gid = blockIdx.x, tid = threadIdx.x;
    buf[tid] = g[(size_t)gid*256 + tid];
    __syncthreads();
    if (tid < 128) {
        float acc = bf0[tid];
        for (int k = 0; k < 256; ++k) acc = fmaf(buf[k], Wf0[k*128 + tid], acc);
        t0[tid] = lrelu(acc);
    }
    __syncthreads();
    if (tid < 64) {
        float acc = bf1[tid];
        for (int k = 0; k < 128; ++k) acc = fmaf(t0[k], Wf1[k*64 + tid], acc);
        t1[tid] = lrelu(acc);
    }
    __syncthreads();
    if (tid < 32) {
        float acc = bf2[tid];
        for (int k = 0; k < 64; ++k) acc = fmaf(t1[k], Wf2[k*32 + tid], acc);
        t2[tid] = lrelu(acc);
    }
    __syncthreads();
    if (tid == 0) {
        float acc = br[0];
        for (int k = 0; k < 32; ++k) acc = fmaf(t2[k], Wr[k], acc);
        out[gid] = acc;
    }
}

extern "C" void kernel_launch(void* const* d_in, const int* in_sizes, int n_in,
                              void* d_out, int out_size, void* d_ws, size_t ws_size,
                              hipStream_t stream)
{
    const float* x     = (const float*)d_in[0];
    const int*   ei    = (const int*)d_in[1];
    const float* ea    = (const float*)d_in[2];
    const int*   batch = (const int*)d_in[3];
    const float* We1=(const float*)d_in[4],  *be1=(const float*)d_in[5];
    const float* W1a=(const float*)d_in[6],  *b1a=(const float*)d_in[7];
    const float* W1b=(const float*)d_in[8],  *b1b=(const float*)d_in[9];
    const float* We2=(const float*)d_in[10], *be2=(const float*)d_in[11];
    const float* W2a=(const float*)d_in[12], *b2a=(const float*)d_in[13];
    const float* W2b=(const float*)d_in[14], *b2b=(const float*)d_in[15];
    const float* Wf0=(const float*)d_in[16], *bf0=(const float*)d_in[17];
    const float* Wf1=(const float*)d_in[18], *bf1=(const float*)d_in[19];
    const float* Wf2=(const float*)d_in[20], *bf2=(const float*)d_in[21];
    const float* Wr =(const float*)d_in[22], *br =(const float*)d_in[23];

    const int N = in_sizes[0] / 32;
    const int E = in_sizes[1] / 2;
    const int G = out_size;
    const int nb = (N + 255) / 256;
    const int nb64 = (N + 63) / 64;

    // ---- workspace layout ----
    // zeroed prefix: [deg N][gbuf G*256][agg1 N*32][agg2 N*64]
    // then: rowptr N, cursor N, bsum 512, csr E int4, h1 N*64, h2 N*256
    char* p = (char*)d_ws;
    int*   deg     = (int*)p;                 p += (size_t)N * 4;
    float* gbuf    = (float*)p;               p += (size_t)G * 256 * 4;
    float* agg1    = (float*)p;               p += (size_t)N * 32 * 4;
    float* agg2    = (float*)p;               p += (size_t)N * 64 * 4;
    size_t zero_bytes = (size_t)(p - (char*)d_ws);
    int*   rowptr  = (int*)p;                 p += (size_t)N * 4;
    int*   cursor  = (int*)p;                 p += (size_t)N * 4;
    int*   bsum    = (int*)p;                 p += 512 * 4;
    // align csr to 16B
    p = (char*)(((uintptr_t)p + 15) & ~(uintptr_t)15);
    int4*  csr     = (int4*)p;                p += (size_t)E * 16;
    float* h1      = (float*)p;               p += (size_t)N * 64 * 4;
    float* h2      = (float*)p;               p += (size_t)N * 256 * 4;

    hipMemsetAsync(d_ws, 0, zero_bytes, stream);

    int eb = (E + 255) / 256;

    // CSR build
    k_hist   <<<eb, 256, 0, stream>>>(ei, deg, E);
    k_scan1  <<<nb, 256, 0, stream>>>(deg, rowptr, bsum, N);
    k_scan2  <<<1, 512, 0, stream>>>(bsum, nb);
    k_scan3  <<<nb, 256, 0, stream>>>(rowptr, cursor, bsum, N);
    k_scatter<<<eb, 256, 0, stream>>>(ei, cursor, csr, E);

    // conv1
    {
        int waves = (E + SPW1 - 1) / SPW1;
        int blocks = (waves + 3) / 4;
        k_agg1<<<blocks, 256, 0, stream>>>(x, ea, We1, be1, csr, agg1, E);
    }
    k_mlp1<<<nb64, 256, 0, stream>>>(x, agg1, W1a, b1a, W1b, b1b, h1, N);

    // conv2
    {
        int waves = (E + SPW2 - 1) / SPW2;
        int blocks = (waves + 3) / 4;
        k_agg2<<<blocks, 256, 0, stream>>>(h1, ea, We2, be2, csr, agg2, E);
    }
    k_mlp2<<<nb64, 256, 0, stream>>>(h1, agg2, W2a, b2a, W2b, b2b, h2, N);

    // pool + head
    k_pool<<<(N + 127) / 128, 256, 0, stream>>>(h2, batch, gbuf, N);
    k_head<<<G, 256, 0, stream>>>(gbuf, Wf0, bf0, Wf1, bf1, Wf2, bf2, Wr, br,
                                  (float*)d_out);
}

// Round 5
// 1042.519 us; speedup vs baseline: 8.2713x; 1.0003x over previous
//
#include <hip/hip_runtime.h>

__device__ __forceinline__ float lrelu(float v){ return v > 0.f ? v : 0.01f*v; }

// ================= CSR build =================================================
__global__ __launch_bounds__(256) void k_hist(
    const int* __restrict__ ei, int* __restrict__ deg, int E)
{
    int e = blockIdx.x * 256 + threadIdx.x;
    if (e >= E) return;
    atomicAdd(&deg[ei[E + e]], 1);
}

__global__ __launch_bounds__(256) void k_scan1(
    const int* __restrict__ deg, int* __restrict__ rowptr,
    int* __restrict__ bsum, int N)
{
    __shared__ int sh[256];
    int t = threadIdx.x;
    int i = blockIdx.x * 256 + t;
    int v = (i < N) ? deg[i] : 0;
    sh[t] = v;
    __syncthreads();
    #pragma unroll
    for (int off = 1; off < 256; off <<= 1) {
        int add = (t >= off) ? sh[t - off] : 0;
        __syncthreads();
        sh[t] += add;
        __syncthreads();
    }
    if (i < N) rowptr[i] = sh[t] - v;
    if (t == 255) bsum[blockIdx.x] = sh[t];
}

__global__ __launch_bounds__(512) void k_scan2(int* __restrict__ bsum, int nb)
{
    __shared__ int sh[512];
    int t = threadIdx.x;
    int v = (t < nb) ? bsum[t] : 0;
    sh[t] = v;
    __syncthreads();
    #pragma unroll
    for (int off = 1; off < 512; off <<= 1) {
        int add = (t >= off) ? sh[t - off] : 0;
        __syncthreads();
        sh[t] += add;
        __syncthreads();
    }
    if (t < nb) bsum[t] = sh[t] - v;
}

__global__ __launch_bounds__(256) void k_scan3(
    int* __restrict__ rowptr, int* __restrict__ cursor,
    const int* __restrict__ bsum, int N)
{
    int i = blockIdx.x * 256 + threadIdx.x;
    if (i >= N) return;
    int rp = rowptr[i] + bsum[i >> 8];
    rowptr[i] = rp;
    cursor[i] = rp;
}

// packed CSR record: x=eid, y=src, z=dst, w=unused
__global__ __launch_bounds__(256) void k_scatter(
    const int* __restrict__ ei, int* __restrict__ cursor,
    int4* __restrict__ csr, int E)
{
    int e = blockIdx.x * 256 + threadIdx.x;
    if (e >= E) return;
    int s = ei[e];
    int d = ei[E + e];
    int slot = atomicAdd(&cursor[d], 1);
    int4 rec; rec.x = e; rec.y = s; rec.z = d; rec.w = 0;
    csr[slot] = rec;
}

// ============ conv1 aggregation: edge-major, 2 slots/wave-iter ===============
#define SPW1 256
__global__ __launch_bounds__(256) void k_agg1(
    const float* __restrict__ x, const float* __restrict__ ea,
    const float* __restrict__ We, const float* __restrict__ be,
    const int4* __restrict__ csr, float* __restrict__ agg, int E)
{
    const int tid = threadIdx.x;
    const int c = tid & 31;
    const int half = (tid >> 5) & 1;
    const int wave = __builtin_amdgcn_readfirstlane((blockIdx.x * 256 + tid) >> 6);
    const long s0 = (long)wave * SPW1;
    if (s0 >= E) return;
    const long send = (s0 + SPW1 < (long)E) ? s0 + SPW1 : (long)E;

    float w[16];
    #pragma unroll
    for (int k = 0; k < 16; ++k) w[k] = We[k * 32 + c];
    const float bias = be[c];

    const bool active = (s0 + half) < send;
    int cur = active ? csr[s0 + half].z : 0;
    float acc = 0.f;

    for (int i = 0; i < SPW1 / 2; ++i) {
        long sl = s0 + 2 * i + half;
        if (sl >= send) break;
        int4 rec = csr[sl];
        if (rec.z != cur) {
            atomicAdd(&agg[(size_t)cur * 32 + c], acc);
            acc = 0.f; cur = rec.z;
        }
        const float4* eap = reinterpret_cast<const float4*>(ea) + (size_t)rec.x * 4;
        float4 e0 = eap[0], e1 = eap[1], e2 = eap[2], e3 = eap[3];
        float m = bias;
        m = fmaf(e0.x, w[0], m);  m = fmaf(e0.y, w[1], m);
        m = fmaf(e0.z, w[2], m);  m = fmaf(e0.w, w[3], m);
        m = fmaf(e1.x, w[4], m);  m = fmaf(e1.y, w[5], m);
        m = fmaf(e1.z, w[6], m);  m = fmaf(e1.w, w[7], m);
        m = fmaf(e2.x, w[8], m);  m = fmaf(e2.y, w[9], m);
        m = fmaf(e2.z, w[10], m); m = fmaf(e2.w, w[11], m);
        m = fmaf(e3.x, w[12], m); m = fmaf(e3.y, w[13], m);
        m = fmaf(e3.z, w[14], m); m = fmaf(e3.w, w[15], m);
        m += x[(size_t)rec.y * 32 + c];
        acc += (m > 0.f ? m : 0.f);
    }
    if (active) atomicAdd(&agg[(size_t)cur * 32 + c], acc);
}

// ============ conv2 aggregation: edge-major, wave-uniform slot ===============
// A dst-run that starts AND ends strictly inside this wave's span is fully
// owned -> plain coalesced store. Boundary runs -> atomicAdd.
#define SPW2 128
__global__ __launch_bounds__(256) void k_agg2(
    const float* __restrict__ h1, const float* __restrict__ ea,
    const float* __restrict__ We, const float* __restrict__ be,
    const int4* __restrict__ csr, float* __restrict__ agg, int E)
{
    const int tid = threadIdx.x;
    const int c = tid & 63;
    const int wave = __builtin_amdgcn_readfirstlane((blockIdx.x * 256 + tid) >> 6);
    const long s0 = (long)wave * SPW2;
    if (s0 >= E) return;
    const long send = (s0 + SPW2 < (long)E) ? s0 + SPW2 : (long)E;

    float w[16];
    #pragma unroll
    for (int k = 0; k < 16; ++k) w[k] = We[k * 64 + c];
    const float bias = be[c];

    int cur = csr[s0].z;          // wave-uniform (s_load)
    bool owned = false;           // current run began inside the span
    float acc = 0.f;

    for (long sl = s0; sl < send; ++sl) {
        int4 rec = csr[sl];       // wave-uniform -> s_load_dwordx4
        if (rec.z != cur) {       // wave-uniform branch
            if (owned) agg[(size_t)cur * 64 + c] = acc;
            else       atomicAdd(&agg[(size_t)cur * 64 + c], acc);
            acc = 0.f; cur = rec.z; owned = true;
        }
        const float4* eap = reinterpret_cast<const float4*>(ea) + (size_t)rec.x * 4;
        float4 e0 = eap[0], e1 = eap[1], e2 = eap[2], e3 = eap[3];
        float m = bias;
        m = fmaf(e0.x, w[0], m);  m = fmaf(e0.y, w[1], m);
        m = fmaf(e0.z, w[2], m);  m = fmaf(e0.w, w[3], m);
        m = fmaf(e1.x, w[4], m);  m = fmaf(e1.y, w[5], m);
        m = fmaf(e1.z, w[6], m);  m = fmaf(e1.w, w[7], m);
        m = fmaf(e2.x, w[8], m);  m = fmaf(e2.y, w[9], m);
        m = fmaf(e2.z, w[10], m); m = fmaf(e2.w, w[11], m);
        m = fmaf(e3.x, w[12], m); m = fmaf(e3.y, w[13], m);
        m = fmaf(e3.z, w[14], m); m = fmaf(e3.w, w[15], m);
        m += h1[(size_t)rec.y * 64 + c];
        acc += (m > 0.f ? m : 0.f);
    }
    // tail run may continue into the next wave's span -> always atomic
    atomicAdd(&agg[(size_t)cur * 64 + c], acc);
}

// ============ conv1 node nn, fused both layers ===============================
__global__ __launch_bounds__(256) void k_mlp1(
    const float* __restrict__ x, const float* __restrict__ agg1,
    const float* __restrict__ W1a, const float* __restrict__ b1a,
    const float* __restrict__ W1b, const float* __restrict__ b1b,
    float* __restrict__ h1, int N)
{
    __shared__ float hs[64][33];
    __shared__ float ts[64][33];
    const int tid = threadIdx.x;
    const int n0 = blockIdx.x * 64;
    const int row = tid & 63;
    const int grp = __builtin_amdgcn_readfirstlane(tid >> 6);

    {
        int r = tid >> 2, c = (tid & 3) * 8;
        int g = n0 + r;
        if (g < N) {
            const float4* xp = reinterpret_cast<const float4*>(x) + (size_t)g*8 + (c>>2);
            const float4* ap = reinterpret_cast<const float4*>(agg1) + (size_t)g*8 + (c>>2);
            #pragma unroll
            for (int q = 0; q < 2; ++q) {
                float4 a = xp[q], b = ap[q];
                hs[r][c+4*q+0]=a.x+b.x; hs[r][c+4*q+1]=a.y+b.y;
                hs[r][c+4*q+2]=a.z+b.z; hs[r][c+4*q+3]=a.w+b.w;
            }
        } else {
            #pragma unroll
            for (int q = 0; q < 8; ++q) hs[r][c+q] = 0.f;
        }
    }
    __syncthreads();

    {
        const int c0 = grp * 8;
        float acc[8];
        #pragma unroll
        for (int i = 0; i < 8; ++i) acc[i] = b1a[c0 + i];
        for (int k = 0; k < 32; ++k) {
            float hv = hs[row][k];
            const float* w = W1a + k*32 + c0;
            #pragma unroll
            for (int i = 0; i < 8; ++i) acc[i] = fmaf(hv, w[i], acc[i]);
        }
        #pragma unroll
        for (int i = 0; i < 8; ++i) ts[row][c0 + i] = lrelu(acc[i]);
    }
    __syncthreads();

    {
        const int c0 = grp * 16;
        float acc[16];
        #pragma unroll
        for (int i = 0; i < 16; ++i) acc[i] = b1b[c0 + i];
        for (int k = 0; k < 32; ++k) {
            float tv = ts[row][k];
            const float* w = W1b + k*64 + c0;
            #pragma unroll
            for (int i = 0; i < 16; ++i) acc[i] = fmaf(tv, w[i], acc[i]);
        }
        int g = n0 + row;
        if (g < N) {
            float4* op = reinterpret_cast<float4*>(h1) + (size_t)g*16 + (c0>>2);
            #pragma unroll
            for (int q = 0; q < 4; ++q) {
                float4 o;
                o.x = lrelu(acc[4*q+0]); o.y = lrelu(acc[4*q+1]);
                o.z = lrelu(acc[4*q+2]); o.w = lrelu(acc[4*q+3]);
                op[q] = o;
            }
        }
    }
}

// ============ conv2 node nn, fused both layers ===============================
// Phase 2 chunked (2 x 32 cols) to keep live state ~90 VGPR -> no scratch spill.
__global__ __launch_bounds__(256, 3) void k_mlp2(
    const float* __restrict__ h1, const float* __restrict__ agg2,
    const float* __restrict__ W2a, const float* __restrict__ b2a,
    const float* __restrict__ W2b, const float* __restrict__ b2b,
    float* __restrict__ h2, int N)
{
    __shared__ float hs[64][65];
    __shared__ float ts[64][129];
    const int tid = threadIdx.x;
    const int n0 = blockIdx.x * 64;
    const int row = tid & 63;
    const int grp = __builtin_amdgcn_readfirstlane(tid >> 6);

    {
        int r = tid >> 2, c = (tid & 3) * 16;
        int g = n0 + r;
        if (g < N) {
            const float4* xp = reinterpret_cast<const float4*>(h1) + (size_t)g*16 + (c>>2);
            const float4* ap = reinterpret_cast<const float4*>(agg2) + (size_t)g*16 + (c>>2);
            #pragma unroll
            for (int q = 0; q < 4; ++q) {
                float4 a = xp[q], b = ap[q];
                hs[r][c+4*q+0]=a.x+b.x; hs[r][c+4*q+1]=a.y+b.y;
                hs[r][c+4*q+2]=a.z+b.z; hs[r][c+4*q+3]=a.w+b.w;
            }
        } else {
            #pragma unroll
            for (int q = 0; q < 16; ++q) hs[r][c+q] = 0.f;
        }
    }
    __syncthreads();

    // phase 1: ts[row][32*grp .. +32] = lrelu(hs[row] @ W2a + b2a)
    {
        const int c0 = grp * 32;
        float acc[32];
        #pragma unroll
        for (int i = 0; i < 32; ++i) acc[i] = b2a[c0 + i];
        for (int k = 0; k < 64; ++k) {
            float hv = hs[row][k];
            const float* w = W2a + k*128 + c0;
            #pragma unroll
            for (int i = 0; i < 32; ++i) acc[i] = fmaf(hv, w[i], acc[i]);
        }
        #pragma unroll
        for (int i = 0; i < 32; ++i) ts[row][c0 + i] = lrelu(acc[i]);
    }
    __syncthreads();

    // phase 2: h2[row][64*grp .. +64], two independent 32-col chunks
    const int g = n0 + row;
    #pragma unroll
    for (int ch = 0; ch < 2; ++ch) {
        const int c0 = grp * 64 + ch * 32;
        float acc[32];
        #pragma unroll
        for (int i = 0; i < 32; ++i) acc[i] = b2b[c0 + i];
        for (int k = 0; k < 128; ++k) {
            float tv = ts[row][k];
            const float* w = W2b + k*256 + c0;
            #pragma unroll
            for (int i = 0; i < 32; ++i) acc[i] = fmaf(tv, w[i], acc[i]);
        }
        if (g < N) {
            float4* op = reinterpret_cast<float4*>(h2) + (size_t)g*64 + (c0>>2);
            #pragma unroll
            for (int q = 0; q < 8; ++q) {
                float4 o;
                o.x = lrelu(acc[4*q+0]); o.y = lrelu(acc[4*q+1]);
                o.z = lrelu(acc[4*q+2]); o.w = lrelu(acc[4*q+3]);
                op[q] = o;
            }
        }
    }
}

// ---------------- global_add_pool over sorted batch ids ------------------------
__global__ __launch_bounds__(256) void k_pool(
    const float* __restrict__ h2, const int* __restrict__ batch,
    float* __restrict__ g, int N)
{
    int c = threadIdx.x;
    int n0 = blockIdx.x * 128;
    int nend = n0 + 128; if (nend > N) nend = N;
    float acc = 0.f;
    int cur = batch[n0];
    for (int n = n0; n < nend; ++n) {
        int b = batch[n];
        if (b != cur) {
            atomicAdd(&g[(size_t)cur*256 + c], acc);
            acc = 0.f; cur = b;
        }
        acc += h2[(size_t)n*256 + c];
    }
    atomicAdd(&g[(size_t)cur*256 + c], acc);
}

// ---------------- head MLP -----------------------------------------------------
__global__ __launch_bounds__(256) void k_head(
    const float* __restrict__ g,
    const float* __restrict__ Wf0, const float* __restrict__ bf0,
    const float* __restrict__ Wf1, const float* __restrict__ bf1,
    const float* __restrict__ Wf2, const float* __restrict__ bf2,
    const float* __restrict__ Wr,  const float* __restrict__ br,
    float* __restrict__ out)
{
    __shared__ float buf[256];
    __shared__ float t0[128];
    __shared__ float t1[64];
    __shared__ float t2[32];
    int gid = blockIdx.x, tid = threadIdx.x;
    buf[tid] = g[(size_t)gid*256 + tid];
    __syncthreads();
    if (tid < 128) {
        float acc = bf0[tid];
        for (int k = 0; k < 256; ++k) acc = fmaf(buf[k], Wf0[k*128 + tid], acc);
        t0[tid] = lrelu(acc);
    }
    __syncthreads();
    if (tid < 64) {
        float acc = bf1[tid];
        for (int k = 0; k < 128; ++k) acc = fmaf(t0[k], Wf1[k*64 + tid], acc);
        t1[tid] = lrelu(acc);
    }
    __syncthreads();
    if (tid < 32) {
        float acc = bf2[tid];
        for (int k = 0; k < 64; ++k) acc = fmaf(t1[k], Wf2[k*32 + tid], acc);
        t2[tid] = lrelu(acc);
    }
    __syncthreads();
    if (tid == 0) {
        float acc = br[0];
        for (int k = 0; k < 32; ++k) acc = fmaf(t2[k], Wr[k], acc);
        out[gid] = acc;
    }
}

extern "C" void kernel_launch(void* const* d_in, const int* in_sizes, int n_in,
                              void* d_out, int out_size, void* d_ws, size_t ws_size,
                              hipStream_t stream)
{
    const float* x     = (const float*)d_in[0];
    const int*   ei    = (const int*)d_in[1];
    const float* ea    = (const float*)d_in[2];
    const int*   batch = (const int*)d_in[3];
    const float* We1=(const float*)d_in[4],  *be1=(const float*)d_in[5];
    const float* W1a=(const float*)d_in[6],  *b1a=(const float*)d_in[7];
    const float* W1b=(const float*)d_in[8],  *b1b=(const float*)d_in[9];
    const float* We2=(const float*)d_in[10], *be2=(const float*)d_in[11];
    const float* W2a=(const float*)d_in[12], *b2a=(const float*)d_in[13];
    const float* W2b=(const float*)d_in[14], *b2b=(const float*)d_in[15];
    const float* Wf0=(const float*)d_in[16], *bf0=(const float*)d_in[17];
    const float* Wf1=(const float*)d_in[18], *bf1=(const float*)d_in[19];
    const float* Wf2=(const float*)d_in[20], *bf2=(const float*)d_in[21];
    const float* Wr =(const float*)d_in[22], *br =(const float*)d_in[23];

    const int N = in_sizes[0] / 32;
    const int E = in_sizes[1] / 2;
    const int G = out_size;
    const int nb = (N + 255) / 256;
    const int nb64 = (N + 63) / 64;

    // ---- workspace layout ----
    char* p = (char*)d_ws;
    int*   deg     = (int*)p;                 p += (size_t)N * 4;
    float* gbuf    = (float*)p;               p += (size_t)G * 256 * 4;
    float* agg1    = (float*)p;               p += (size_t)N * 32 * 4;
    float* agg2    = (float*)p;               p += (size_t)N * 64 * 4;
    size_t zero_bytes = (size_t)(p - (char*)d_ws);
    int*   rowptr  = (int*)p;                 p += (size_t)N * 4;
    int*   cursor  = (int*)p;                 p += (size_t)N * 4;
    int*   bsum    = (int*)p;                 p += 512 * 4;
    p = (char*)(((uintptr_t)p + 15) & ~(uintptr_t)15);
    int4*  csr     = (int4*)p;                p += (size_t)E * 16;
    float* h1      = (float*)p;               p += (size_t)N * 64 * 4;
    float* h2      = (float*)p;               p += (size_t)N * 256 * 4;

    hipMemsetAsync(d_ws, 0, zero_bytes, stream);

    int eb = (E + 255) / 256;

    // CSR build
    k_hist   <<<eb, 256, 0, stream>>>(ei, deg, E);
    k_scan1  <<<nb, 256, 0, stream>>>(deg, rowptr, bsum, N);
    k_scan2  <<<1, 512, 0, stream>>>(bsum, nb);
    k_scan3  <<<nb, 256, 0, stream>>>(rowptr, cursor, bsum, N);
    k_scatter<<<eb, 256, 0, stream>>>(ei, cursor, csr, E);

    // conv1
    {
        int waves = (E + SPW1 - 1) / SPW1;
        int blocks = (waves + 3) / 4;
        k_agg1<<<blocks, 256, 0, stream>>>(x, ea, We1, be1, csr, agg1, E);
    }
    k_mlp1<<<nb64, 256, 0, stream>>>(x, agg1, W1a, b1a, W1b, b1b, h1, N);

    // conv2
    {
        int waves = (E + SPW2 - 1) / SPW2;
        int blocks = (waves + 3) / 4;
        k_agg2<<<blocks, 256, 0, stream>>>(h1, ea, We2, be2, csr, agg2, E);
    }
    k_mlp2<<<nb64, 256, 0, stream>>>(h1, agg2, W2a, b2a, W2b, b2b, h2, N);

    // pool + head
    k_pool<<<(N + 127) / 128, 256, 0, stream>>>(h2, batch, gbuf, N);
    k_head<<<G, 256, 0, stream>>>(gbuf, Wf0, bf0, Wf1, bf1, Wf2, bf2, Wr, br,
                                  (float*)d_out);
}

// Round 6
// 991.404 us; speedup vs baseline: 8.6977x; 1.0516x over previous
//
#include <hip/hip_runtime.h>

__device__ __forceinline__ float lrelu(float v){ return v > 0.f ? v : 0.01f*v; }

// ================= CSR build =================================================
__global__ __launch_bounds__(256) void k_hist(
    const int* __restrict__ ei, int* __restrict__ deg, int E)
{
    int e = blockIdx.x * 256 + threadIdx.x;
    if (e >= E) return;
    atomicAdd(&deg[ei[E + e]], 1);
}

__global__ __launch_bounds__(256) void k_scan1(
    const int* __restrict__ deg, int* __restrict__ rowptr,
    int* __restrict__ bsum, int N)
{
    __shared__ int sh[256];
    int t = threadIdx.x;
    int i = blockIdx.x * 256 + t;
    int v = (i < N) ? deg[i] : 0;
    sh[t] = v;
    __syncthreads();
    #pragma unroll
    for (int off = 1; off < 256; off <<= 1) {
        int add = (t >= off) ? sh[t - off] : 0;
        __syncthreads();
        sh[t] += add;
        __syncthreads();
    }
    if (i < N) rowptr[i] = sh[t] - v;
    if (t == 255) bsum[blockIdx.x] = sh[t];
}

__global__ __launch_bounds__(512) void k_scan2(int* __restrict__ bsum, int nb)
{
    __shared__ int sh[512];
    int t = threadIdx.x;
    int v = (t < nb) ? bsum[t] : 0;
    sh[t] = v;
    __syncthreads();
    #pragma unroll
    for (int off = 1; off < 512; off <<= 1) {
        int add = (t >= off) ? sh[t - off] : 0;
        __syncthreads();
        sh[t] += add;
        __syncthreads();
    }
    if (t < nb) bsum[t] = sh[t] - v;
}

__global__ __launch_bounds__(256) void k_scan3(
    int* __restrict__ rowptr, int* __restrict__ cursor,
    const int* __restrict__ bsum, int N)
{
    int i = blockIdx.x * 256 + threadIdx.x;
    if (i >= N) return;
    int rp = rowptr[i] + bsum[i >> 8];
    rowptr[i] = rp;
    cursor[i] = rp;
}

// packed CSR record: x=eid, y=src, z=dst, w=unused
__global__ __launch_bounds__(256) void k_scatter(
    const int* __restrict__ ei, int* __restrict__ cursor,
    int4* __restrict__ csr, int E)
{
    int e = blockIdx.x * 256 + threadIdx.x;
    if (e >= E) return;
    int s = ei[e];
    int d = ei[E + e];
    int slot = atomicAdd(&cursor[d], 1);
    int4 rec; rec.x = e; rec.y = s; rec.z = d; rec.w = 0;
    csr[slot] = rec;
}

// ============ conv1 aggregation: edge-major, SW-pipelined ====================
#define SPW1 128
__global__ __launch_bounds__(256) void k_agg1(
    const float* __restrict__ x, const float* __restrict__ ea,
    const float* __restrict__ We, const float* __restrict__ be,
    const int4* __restrict__ csr, float* __restrict__ agg, int E)
{
    const int tid = threadIdx.x;
    const int c = tid & 31;
    const int half = (tid >> 5) & 1;
    const int wave = __builtin_amdgcn_readfirstlane((blockIdx.x * 256 + tid) >> 6);
    const long s0 = (long)wave * SPW1;
    if (s0 >= E) return;
    const long send = (s0 + SPW1 < (long)E) ? s0 + SPW1 : (long)E;

    float w[16];
    #pragma unroll
    for (int k = 0; k < 16; ++k) w[k] = We[k * 32 + c];
    const float bias = be[c];

    long sl = s0 + half;
    if (sl >= send) return;

    int4 rec = csr[sl];
    float xv = x[(size_t)rec.y * 32 + c];
    float4 e0, e1, e2, e3;
    {
        const float4* p = reinterpret_cast<const float4*>(ea) + (size_t)rec.x * 4;
        e0 = p[0]; e1 = p[1]; e2 = p[2]; e3 = p[3];
    }
    int cur = rec.z;
    float acc = 0.f;
    bool more = true;
    do {
        long nxt = sl + 2;
        more = (nxt < send);
        int4 recn; float xvn; float4 f0, f1, f2, f3;
        if (more) {                         // prefetch next slot
            recn = csr[nxt];
            xvn = x[(size_t)recn.y * 32 + c];
            const float4* p = reinterpret_cast<const float4*>(ea) + (size_t)recn.x * 4;
            f0 = p[0]; f1 = p[1]; f2 = p[2]; f3 = p[3];
        }
        if (rec.z != cur) {
            atomicAdd(&agg[(size_t)cur * 32 + c], acc);
            acc = 0.f; cur = rec.z;
        }
        float m = bias;
        m = fmaf(e0.x, w[0], m);  m = fmaf(e0.y, w[1], m);
        m = fmaf(e0.z, w[2], m);  m = fmaf(e0.w, w[3], m);
        m = fmaf(e1.x, w[4], m);  m = fmaf(e1.y, w[5], m);
        m = fmaf(e1.z, w[6], m);  m = fmaf(e1.w, w[7], m);
        m = fmaf(e2.x, w[8], m);  m = fmaf(e2.y, w[9], m);
        m = fmaf(e2.z, w[10], m); m = fmaf(e2.w, w[11], m);
        m = fmaf(e3.x, w[12], m); m = fmaf(e3.y, w[13], m);
        m = fmaf(e3.z, w[14], m); m = fmaf(e3.w, w[15], m);
        m += xv;
        acc += (m > 0.f ? m : 0.f);
        if (more) {
            rec = recn; xv = xvn;
            e0 = f0; e1 = f1; e2 = f2; e3 = f3;
        }
        sl = nxt;
    } while (more);
    atomicAdd(&agg[(size_t)cur * 32 + c], acc);
}

// ============ conv2 aggregation: edge-major, wave-uniform, SW-pipelined ======
#define SPW2 64
__global__ __launch_bounds__(256) void k_agg2(
    const float* __restrict__ h1, const float* __restrict__ ea,
    const float* __restrict__ We, const float* __restrict__ be,
    const int4* __restrict__ csr, float* __restrict__ agg, int E)
{
    const int tid = threadIdx.x;
    const int c = tid & 63;
    const int wave = __builtin_amdgcn_readfirstlane((blockIdx.x * 256 + tid) >> 6);
    const long s0 = (long)wave * SPW2;
    if (s0 >= E) return;
    const long send = (s0 + SPW2 < (long)E) ? s0 + SPW2 : (long)E;

    float w[16];
    #pragma unroll
    for (int k = 0; k < 16; ++k) w[k] = We[k * 64 + c];
    const float bias = be[c];

    long sl = s0;
    int4 rec = csr[sl];                     // wave-uniform -> s_load
    float hv = h1[(size_t)rec.y * 64 + c];
    float4 e0, e1, e2, e3;
    {
        const float4* p = reinterpret_cast<const float4*>(ea) + (size_t)rec.x * 4;
        e0 = p[0]; e1 = p[1]; e2 = p[2]; e3 = p[3];
    }
    int cur = rec.z;
    bool owned = false;
    float acc = 0.f;
    bool more = true;
    do {
        long nxt = sl + 1;
        more = (nxt < send);
        int4 recn; float hvn; float4 f0, f1, f2, f3;
        if (more) {                         // prefetch next slot
            recn = csr[nxt];
            hvn = h1[(size_t)recn.y * 64 + c];
            const float4* p = reinterpret_cast<const float4*>(ea) + (size_t)recn.x * 4;
            f0 = p[0]; f1 = p[1]; f2 = p[2]; f3 = p[3];
        }
        if (rec.z != cur) {                 // wave-uniform branch
            if (owned) agg[(size_t)cur * 64 + c] = acc;
            else       atomicAdd(&agg[(size_t)cur * 64 + c], acc);
            acc = 0.f; cur = rec.z; owned = true;
        }
        float m = bias;
        m = fmaf(e0.x, w[0], m);  m = fmaf(e0.y, w[1], m);
        m = fmaf(e0.z, w[2], m);  m = fmaf(e0.w, w[3], m);
        m = fmaf(e1.x, w[4], m);  m = fmaf(e1.y, w[5], m);
        m = fmaf(e1.z, w[6], m);  m = fmaf(e1.w, w[7], m);
        m = fmaf(e2.x, w[8], m);  m = fmaf(e2.y, w[9], m);
        m = fmaf(e2.z, w[10], m); m = fmaf(e2.w, w[11], m);
        m = fmaf(e3.x, w[12], m); m = fmaf(e3.y, w[13], m);
        m = fmaf(e3.z, w[14], m); m = fmaf(e3.w, w[15], m);
        m += hv;
        acc += (m > 0.f ? m : 0.f);
        if (more) {
            rec = recn; hv = hvn;
            e0 = f0; e1 = f1; e2 = f2; e3 = f3;
        }
        sl = nxt;
    } while (more);
    atomicAdd(&agg[(size_t)cur * 64 + c], acc);   // tail may cross wave boundary
}

// ============ conv1 node nn, fused; row in registers, ts-only LDS ============
__global__ __launch_bounds__(256, 4) void k_mlp1(
    const float* __restrict__ x, const float* __restrict__ agg1,
    const float* __restrict__ W1a, const float* __restrict__ b1a,
    const float* __restrict__ W1b, const float* __restrict__ b1b,
    float* __restrict__ h1, int N)
{
    __shared__ float ts[64][33];
    const int tid = threadIdx.x;
    const int n0 = blockIdx.x * 64;
    const int row = tid & 63;
    const int grp = __builtin_amdgcn_readfirstlane(tid >> 6);
    const int g = n0 + row;

    float hv[32];
    if (g < N) {
        const float4* xp = reinterpret_cast<const float4*>(x) + (size_t)g * 8;
        const float4* ap = reinterpret_cast<const float4*>(agg1) + (size_t)g * 8;
        #pragma unroll
        for (int q = 0; q < 8; ++q) {
            float4 a = xp[q], b = ap[q];
            hv[4*q+0]=a.x+b.x; hv[4*q+1]=a.y+b.y;
            hv[4*q+2]=a.z+b.z; hv[4*q+3]=a.w+b.w;
        }
    } else {
        #pragma unroll
        for (int q = 0; q < 32; ++q) hv[q] = 0.f;
    }

    // phase 1: ts[row][8*grp .. +8] = lrelu(hv @ W1a + b1a)
    {
        const int c0 = grp * 8;
        float acc[8];
        #pragma unroll
        for (int i = 0; i < 8; ++i) acc[i] = b1a[c0 + i];
        for (int k = 0; k < 32; ++k) {
            float h = hv[k];
            const float* w = W1a + k*32 + c0;
            #pragma unroll
            for (int i = 0; i < 8; ++i) acc[i] = fmaf(h, w[i], acc[i]);
        }
        #pragma unroll
        for (int i = 0; i < 8; ++i) ts[row][c0 + i] = lrelu(acc[i]);
    }
    __syncthreads();

    // phase 2: h1[row][16*grp .. +16] = lrelu(ts[row] @ W1b + b1b)
    {
        const int c0 = grp * 16;
        float acc[16];
        #pragma unroll
        for (int i = 0; i < 16; ++i) acc[i] = b1b[c0 + i];
        for (int k = 0; k < 32; ++k) {
            float tv = ts[row][k];
            const float* w = W1b + k*64 + c0;
            #pragma unroll
            for (int i = 0; i < 16; ++i) acc[i] = fmaf(tv, w[i], acc[i]);
        }
        if (g < N) {
            float4* op = reinterpret_cast<float4*>(h1) + (size_t)g*16 + (c0>>2);
            #pragma unroll
            for (int q = 0; q < 4; ++q) {
                float4 o;
                o.x = lrelu(acc[4*q+0]); o.y = lrelu(acc[4*q+1]);
                o.z = lrelu(acc[4*q+2]); o.w = lrelu(acc[4*q+3]);
                op[q] = o;
            }
        }
    }
}

// ============ conv2 node nn, fused; row in registers, ts-only LDS ============
// LDS 33KB -> 4 blocks/CU; hv[64]+acc[32] ~ 110 VGPR under (256,4) cap 128.
__global__ __launch_bounds__(256, 4) void k_mlp2(
    const float* __restrict__ h1, const float* __restrict__ agg2,
    const float* __restrict__ W2a, const float* __restrict__ b2a,
    const float* __restrict__ W2b, const float* __restrict__ b2b,
    float* __restrict__ h2, int N)
{
    __shared__ float ts[64][129];
    const int tid = threadIdx.x;
    const int n0 = blockIdx.x * 64;
    const int row = tid & 63;
    const int grp = __builtin_amdgcn_readfirstlane(tid >> 6);
    const int g = n0 + row;

    float hv[64];
    if (g < N) {
        const float4* xp = reinterpret_cast<const float4*>(h1) + (size_t)g * 16;
        const float4* ap = reinterpret_cast<const float4*>(agg2) + (size_t)g * 16;
        #pragma unroll
        for (int q = 0; q < 16; ++q) {
            float4 a = xp[q], b = ap[q];
            hv[4*q+0]=a.x+b.x; hv[4*q+1]=a.y+b.y;
            hv[4*q+2]=a.z+b.z; hv[4*q+3]=a.w+b.w;
        }
    } else {
        #pragma unroll
        for (int q = 0; q < 64; ++q) hv[q] = 0.f;
    }

    // phase 1: ts[row][32*grp .. +32] = lrelu(hv @ W2a + b2a)
    {
        const int c0 = grp * 32;
        float acc[32];
        #pragma unroll
        for (int i = 0; i < 32; ++i) acc[i] = b2a[c0 + i];
        for (int k = 0; k < 64; ++k) {
            float h = hv[k];
            const float* w = W2a + k*128 + c0;
            #pragma unroll
            for (int i = 0; i < 32; ++i) acc[i] = fmaf(h, w[i], acc[i]);
        }
        #pragma unroll
        for (int i = 0; i < 32; ++i) ts[row][c0 + i] = lrelu(acc[i]);
    }
    __syncthreads();

    // phase 2: h2[row][64*grp .. +64], two 32-col chunks (bounded live state)
    #pragma unroll
    for (int ch = 0; ch < 2; ++ch) {
        const int c0 = grp * 64 + ch * 32;
        float acc[32];
        #pragma unroll
        for (int i = 0; i < 32; ++i) acc[i] = b2b[c0 + i];
        for (int k = 0; k < 128; ++k) {
            float tv = ts[row][k];
            const float* w = W2b + k*256 + c0;
            #pragma unroll
            for (int i = 0; i < 32; ++i) acc[i] = fmaf(tv, w[i], acc[i]);
        }
        if (g < N) {
            float4* op = reinterpret_cast<float4*>(h2) + (size_t)g*64 + (c0>>2);
            #pragma unroll
            for (int q = 0; q < 8; ++q) {
                float4 o;
                o.x = lrelu(acc[4*q+0]); o.y = lrelu(acc[4*q+1]);
                o.z = lrelu(acc[4*q+2]); o.w = lrelu(acc[4*q+3]);
                op[q] = o;
            }
        }
    }
}

// ---------------- global_add_pool over sorted batch ids ------------------------
__global__ __launch_bounds__(256) void k_pool(
    const float* __restrict__ h2, const int* __restrict__ batch,
    float* __restrict__ g, int N)
{
    int c = threadIdx.x;
    int n0 = blockIdx.x * 128;
    int nend = n0 + 128; if (nend > N) nend = N;
    float acc = 0.f;
    int cur = batch[n0];
    for (int n = n0; n < nend; ++n) {
        int b = batch[n];
        if (b != cur) {
            atomicAdd(&g[(size_t)cur*256 + c], acc);
            acc = 0.f; cur = b;
        }
        acc += h2[(size_t)n*256 + c];
    }
    atomicAdd(&g[(size_t)cur*256 + c], acc);
}

// ---------------- head MLP -----------------------------------------------------
__global__ __launch_bounds__(256) void k_head(
    const float* __restrict__ g,
    const float* __restrict__ Wf0, const float* __restrict__ bf0,
    const float* __restrict__ Wf1, const float* __restrict__ bf1,
    const float* __restrict__ Wf2, const float* __restrict__ bf2,
    const float* __restrict__ Wr,  const float* __restrict__ br,
    float* __restrict__ out)
{
    __shared__ float buf[256];
    __shared__ float t0[128];
    __shared__ float t1[64];
    __shared__ float t2[32];
    int gid = blockIdx.x, tid = threadIdx.x;
    buf[tid] = g[(size_t)gid*256 + tid];
    __syncthreads();
    if (tid < 128) {
        float acc = bf0[tid];
        for (int k = 0; k < 256; ++k) acc = fmaf(buf[k], Wf0[k*128 + tid], acc);
        t0[tid] = lrelu(acc);
    }
    __syncthreads();
    if (tid < 64) {
        float acc = bf1[tid];
        for (int k = 0; k < 128; ++k) acc = fmaf(t0[k], Wf1[k*64 + tid], acc);
        t1[tid] = lrelu(acc);
    }
    __syncthreads();
    if (tid < 32) {
        float acc = bf2[tid];
        for (int k = 0; k < 64; ++k) acc = fmaf(t1[k], Wf2[k*32 + tid], acc);
        t2[tid] = lrelu(acc);
    }
    __syncthreads();
    if (tid == 0) {
        float acc = br[0];
        for (int k = 0; k < 32; ++k) acc = fmaf(t2[k], Wr[k], acc);
        out[gid] = acc;
    }
}

extern "C" void kernel_launch(void* const* d_in, const int* in_sizes, int n_in,
                              void* d_out, int out_size, void* d_ws, size_t ws_size,
                              hipStream_t stream)
{
    const float* x     = (const float*)d_in[0];
    const int*   ei    = (const int*)d_in[1];
    const float* ea    = (const float*)d_in[2];
    const int*   batch = (const int*)d_in[3];
    const float* We1=(const float*)d_in[4],  *be1=(const float*)d_in[5];
    const float* W1a=(const float*)d_in[6],  *b1a=(const float*)d_in[7];
    const float* W1b=(const float*)d_in[8],  *b1b=(const float*)d_in[9];
    const float* We2=(const float*)d_in[10], *be2=(const float*)d_in[11];
    const float* W2a=(const float*)d_in[12], *b2a=(const float*)d_in[13];
    const float* W2b=(const float*)d_in[14], *b2b=(const float*)d_in[15];
    const float* Wf0=(const float*)d_in[16], *bf0=(const float*)d_in[17];
    const float* Wf1=(const float*)d_in[18], *bf1=(const float*)d_in[19];
    const float* Wf2=(const float*)d_in[20], *bf2=(const float*)d_in[21];
    const float* Wr =(const float*)d_in[22], *br =(const float*)d_in[23];

    const int N = in_sizes[0] / 32;
    const int E = in_sizes[1] / 2;
    const int G = out_size;
    const int nb = (N + 255) / 256;
    const int nb64 = (N + 63) / 64;

    // ---- workspace layout ----
    char* p = (char*)d_ws;
    int*   deg     = (int*)p;                 p += (size_t)N * 4;
    float* gbuf    = (float*)p;               p += (size_t)G * 256 * 4;
    float* agg1    = (float*)p;               p += (size_t)N * 32 * 4;
    float* agg2    = (float*)p;               p += (size_t)N * 64 * 4;
    size_t zero_bytes = (size_t)(p - (char*)d_ws);
    int*   rowptr  = (int*)p;                 p += (size_t)N * 4;
    int*   cursor  = (int*)p;                 p += (size_t)N * 4;
    int*   bsum    = (int*)p;                 p += 512 * 4;
    p = (char*)(((uintptr_t)p + 15) & ~(uintptr_t)15);
    int4*  csr     = (int4*)p;                p += (size_t)E * 16;
    float* h1      = (float*)p;               p += (size_t)N * 64 * 4;
    float* h2      = (float*)p;               p += (size_t)N * 256 * 4;

    hipMemsetAsync(d_ws, 0, zero_bytes, stream);

    int eb = (E + 255) / 256;

    // CSR build
    k_hist   <<<eb, 256, 0, stream>>>(ei, deg, E);
    k_scan1  <<<nb, 256, 0, stream>>>(deg, rowptr, bsum, N);
    k_scan2  <<<1, 512, 0, stream>>>(bsum, nb);
    k_scan3  <<<nb, 256, 0, stream>>>(rowptr, cursor, bsum, N);
    k_scatter<<<eb, 256, 0, stream>>>(ei, cursor, csr, E);

    // conv1
    {
        int waves = (E + SPW1 - 1) / SPW1;
        int blocks = (waves + 3) / 4;
        k_agg1<<<blocks, 256, 0, stream>>>(x, ea, We1, be1, csr, agg1, E);
    }
    k_mlp1<<<nb64, 256, 0, stream>>>(x, agg1, W1a, b1a, W1b, b1b, h1, N);

    // conv2
    {
        int waves = (E + SPW2 - 1) / SPW2;
        int blocks = (waves + 3) / 4;
        k_agg2<<<blocks, 256, 0, stream>>>(h1, ea, We2, be2, csr, agg2, E);
    }
    k_mlp2<<<nb64, 256, 0, stream>>>(h1, agg2, W2a, b2a, W2b, b2b, h2, N);

    // pool + head
    k_pool<<<(N + 127) / 128, 256, 0, stream>>>(h2, batch, gbuf, N);
    k_head<<<G, 256, 0, stream>>>(gbuf, Wf0, bf0, Wf1, bf1, Wf2, bf2, Wr, br,
                                  (float*)d_out);
}